// Round 1
// baseline (2202.360 us; speedup 1.0000x reference)
//
#include <hip/hip_runtime.h>
#include <hip/hip_bf16.h>
#include <math.h>

#define BATCH   4
#define SEQ     1024
#define DMODEL  2048
#define NHEADS  16
#define NGROUPS 2
#define HDIM    128
#define ROWS    (BATCH * SEQ)      // 4096
#define KVD     (NGROUPS * HDIM)   // 256

// ---------------------------------------------------------------------------
// RoPE tables: sin/cos[p][j], p in [0,SEQ), j in [0,64)
// ---------------------------------------------------------------------------
__global__ void rope_table_kernel(float* __restrict__ sin_t, float* __restrict__ cos_t) {
    int idx = blockIdx.x * 256 + threadIdx.x;   // SEQ*64 total
    int p = idx >> 6, j = idx & 63;
    float inv = powf(10000.0f, -(float)j * (1.0f / 64.0f));
    float f = (float)p * inv;
    sin_t[idx] = sinf(f);
    cos_t[idx] = cosf(f);
}

// ---------------------------------------------------------------------------
// In-place RoPE: x is [ROWS][nheads*128]; pair (j, j+64) rotated by freq j.
// ---------------------------------------------------------------------------
__global__ void rope_apply_kernel(float* __restrict__ x,
                                  const float* __restrict__ sin_t,
                                  const float* __restrict__ cos_t,
                                  int nheads) {
    int idx = blockIdx.x * 256 + threadIdx.x;   // ROWS*nheads*64 total
    int j = idx & 63;
    int t = idx >> 6;            // row*nheads + h
    int h = t % nheads;
    int row = t / nheads;
    int p = row & (SEQ - 1);
    float s = sin_t[p * 64 + j];
    float c = cos_t[p * 64 + j];
    float* base = x + (size_t)row * (nheads * HDIM) + h * HDIM;
    float x1 = base[j];
    float x2 = base[j + 64];
    base[j]      = x1 * c - x2 * s;
    base[j + 64] = x2 * c + x1 * s;
}

// ---------------------------------------------------------------------------
// fp32 GEMM + bias: C[M][N] = A[M][K] @ B[K][N] + bias[N]
// 128x128 block tile, 16 K-step, 256 threads, 8x8 micro-tile.
// ---------------------------------------------------------------------------
#define GBM 128
#define GBN 128
#define GBK 16

__global__ __launch_bounds__(256)
void sgemm_bias_kernel(const float* __restrict__ A, const float* __restrict__ B,
                       const float* __restrict__ bias, float* __restrict__ C,
                       int M, int N, int K) {
    __shared__ float As[GBK][GBM + 4];   // transposed A tile, stride 132
    __shared__ float Bs[GBK][GBN];
    const int tid  = threadIdx.x;
    const int row0 = blockIdx.y * GBM;
    const int col0 = blockIdx.x * GBN;
    const int tr = (tid >> 4) << 3;      // 0..120, thread row base
    const int tc = (tid & 15) << 3;      // 0..120, thread col base

    float acc[8][8];
#pragma unroll
    for (int i = 0; i < 8; ++i)
#pragma unroll
        for (int j = 0; j < 8; ++j) acc[i][j] = 0.0f;

    for (int k0 = 0; k0 < K; k0 += GBK) {
        __syncthreads();
#pragma unroll
        for (int i = 0; i < 2; ++i) {
            int f = tid + 256 * i;                 // 0..511
            int ar = f >> 2, ak = (f & 3) << 2;    // A: 128 rows x 16 k
            const float4 av = *reinterpret_cast<const float4*>(
                A + (size_t)(row0 + ar) * K + k0 + ak);
            As[ak + 0][ar] = av.x; As[ak + 1][ar] = av.y;
            As[ak + 2][ar] = av.z; As[ak + 3][ar] = av.w;
            int bk = f >> 5, bc = (f & 31) << 2;   // B: 16 k x 128 cols
            *reinterpret_cast<float4*>(&Bs[bk][bc]) =
                *reinterpret_cast<const float4*>(B + (size_t)(k0 + bk) * N + col0 + bc);
        }
        __syncthreads();
#pragma unroll
        for (int kk = 0; kk < GBK; ++kk) {
            float a[8], b[8];
            *reinterpret_cast<float4*>(&a[0]) = *reinterpret_cast<const float4*>(&As[kk][tr]);
            *reinterpret_cast<float4*>(&a[4]) = *reinterpret_cast<const float4*>(&As[kk][tr + 4]);
            *reinterpret_cast<float4*>(&b[0]) = *reinterpret_cast<const float4*>(&Bs[kk][tc]);
            *reinterpret_cast<float4*>(&b[4]) = *reinterpret_cast<const float4*>(&Bs[kk][tc + 4]);
#pragma unroll
            for (int i = 0; i < 8; ++i)
#pragma unroll
                for (int j = 0; j < 8; ++j)
                    acc[i][j] = fmaf(a[i], b[j], acc[i][j]);
        }
    }

    float bv[8];
    *reinterpret_cast<float4*>(&bv[0]) = *reinterpret_cast<const float4*>(bias + col0 + tc);
    *reinterpret_cast<float4*>(&bv[4]) = *reinterpret_cast<const float4*>(bias + col0 + tc + 4);
#pragma unroll
    for (int i = 0; i < 8; ++i) {
        float4 o0, o1;
        o0.x = acc[i][0] + bv[0]; o0.y = acc[i][1] + bv[1];
        o0.z = acc[i][2] + bv[2]; o0.w = acc[i][3] + bv[3];
        o1.x = acc[i][4] + bv[4]; o1.y = acc[i][5] + bv[5];
        o1.z = acc[i][6] + bv[6]; o1.w = acc[i][7] + bv[7];
        float* cp = C + (size_t)(row0 + tr + i) * N + col0 + tc;
        *reinterpret_cast<float4*>(cp)     = o0;
        *reinterpret_cast<float4*>(cp + 4) = o1;
    }
}

// ---------------------------------------------------------------------------
// Fused flash attention (fp32). Grid: (SEQ/64, NHEADS, BATCH), 256 threads.
// Q,K transposed in LDS; V natural. S/P in registers (4x4 per thread).
// Softmax row stats via width-16 shuffles. Output written in place over q.
// ---------------------------------------------------------------------------
__global__ __launch_bounds__(256)
void attn_kernel(const float* __restrict__ q, const float* __restrict__ k,
                 const float* __restrict__ v, float* __restrict__ o) {
    __shared__ float Qt[HDIM][64 + 4];   // Qt[d][qi]
    __shared__ float Kt[HDIM][64 + 4];   // Kt[d][tj]
    __shared__ float Vs[64][HDIM + 4];   // Vs[tj][d]

    const int tid = threadIdx.x;
    const int qt0 = blockIdx.x * 64;
    const int h   = blockIdx.y;
    const int bb  = blockIdx.z;
    const int g   = h >> 3;              // 8 heads per kv group
    const int sq  = tid >> 4;            // 0..15 -> rows 4sq..4sq+3
    const int st  = tid & 15;            // 0..15 -> cols 4st..4st+3 (S), d 8st..8st+7 (O)

    // load Q tile transposed
#pragma unroll
    for (int i = 0; i < 8; ++i) {
        int f = tid + 256 * i;
        int r = f >> 5, c4 = (f & 31) << 2;
        const float4 vq = *reinterpret_cast<const float4*>(
            q + ((size_t)(bb * SEQ + qt0 + r) * NHEADS + h) * HDIM + c4);
        Qt[c4 + 0][r] = vq.x; Qt[c4 + 1][r] = vq.y;
        Qt[c4 + 2][r] = vq.z; Qt[c4 + 3][r] = vq.w;
    }

    float m_run[4], l_run[4], oacc[4][8];
#pragma unroll
    for (int i = 0; i < 4; ++i) {
        m_run[i] = -1e30f; l_run[i] = 0.0f;
#pragma unroll
        for (int c = 0; c < 8; ++c) oacc[i][c] = 0.0f;
    }
    const float sc = 0.08838834764831845f;   // 1/sqrt(128)

    for (int t0 = 0; t0 < SEQ; t0 += 64) {
        __syncthreads();   // prev iter done with Kt/Vs (and Qt visible, iter 0)
#pragma unroll
        for (int i = 0; i < 8; ++i) {
            int f = tid + 256 * i;
            int r = f >> 5, c4 = (f & 31) << 2;
            size_t kvoff = ((size_t)(bb * SEQ + t0 + r) * NGROUPS + g) * HDIM + c4;
            const float4 kv4 = *reinterpret_cast<const float4*>(k + kvoff);
            Kt[c4 + 0][r] = kv4.x; Kt[c4 + 1][r] = kv4.y;
            Kt[c4 + 2][r] = kv4.z; Kt[c4 + 3][r] = kv4.w;
            *reinterpret_cast<float4*>(&Vs[r][c4]) =
                *reinterpret_cast<const float4*>(v + kvoff);
        }
        __syncthreads();

        // ---- S = Q K^T (4x4 per thread, in registers) ----
        float sacc[4][4];
#pragma unroll
        for (int i = 0; i < 4; ++i)
#pragma unroll
            for (int j = 0; j < 4; ++j) sacc[i][j] = 0.0f;

#pragma unroll 8
        for (int d = 0; d < HDIM; ++d) {
            float qa[4], kb[4];
            *reinterpret_cast<float4*>(&qa[0]) =
                *reinterpret_cast<const float4*>(&Qt[d][sq << 2]);
            *reinterpret_cast<float4*>(&kb[0]) =
                *reinterpret_cast<const float4*>(&Kt[d][st << 2]);
#pragma unroll
            for (int i = 0; i < 4; ++i)
#pragma unroll
                for (int j = 0; j < 4; ++j)
                    sacc[i][j] = fmaf(qa[i], kb[j], sacc[i][j]);
        }

        // ---- online softmax (row stats across the 16 lanes of this row group)
#pragma unroll
        for (int i = 0; i < 4; ++i) {
#pragma unroll
            for (int j = 0; j < 4; ++j) sacc[i][j] *= sc;
            float rm = fmaxf(fmaxf(sacc[i][0], sacc[i][1]),
                             fmaxf(sacc[i][2], sacc[i][3]));
            rm = fmaxf(rm, __shfl_xor(rm, 1, 16));
            rm = fmaxf(rm, __shfl_xor(rm, 2, 16));
            rm = fmaxf(rm, __shfl_xor(rm, 4, 16));
            rm = fmaxf(rm, __shfl_xor(rm, 8, 16));
            float mn  = fmaxf(m_run[i], rm);
            float scl = __expf(m_run[i] - mn);
            float ps = 0.0f;
#pragma unroll
            for (int j = 0; j < 4; ++j) {
                sacc[i][j] = __expf(sacc[i][j] - mn);
                ps += sacc[i][j];
            }
            ps += __shfl_xor(ps, 1, 16);
            ps += __shfl_xor(ps, 2, 16);
            ps += __shfl_xor(ps, 4, 16);
            ps += __shfl_xor(ps, 8, 16);
            l_run[i] = l_run[i] * scl + ps;
            m_run[i] = mn;
#pragma unroll
            for (int c = 0; c < 8; ++c) oacc[i][c] *= scl;
        }

        // ---- O += P V  (broadcast P across the row group via shfl) ----
#pragma unroll 4
        for (int tj4 = 0; tj4 < 16; ++tj4) {
#pragma unroll
            for (int jj = 0; jj < 4; ++jj) {
                float pr[4];
#pragma unroll
                for (int i = 0; i < 4; ++i)
                    pr[i] = __shfl(sacc[i][jj], tj4, 16);
                int tj = (tj4 << 2) | jj;
                float vv[8];
                const float* vp = &Vs[tj][st << 3];
                *reinterpret_cast<float4*>(&vv[0]) = *reinterpret_cast<const float4*>(vp);
                *reinterpret_cast<float4*>(&vv[4]) = *reinterpret_cast<const float4*>(vp + 4);
#pragma unroll
                for (int i = 0; i < 4; ++i)
#pragma unroll
                    for (int c = 0; c < 8; ++c)
                        oacc[i][c] = fmaf(pr[i], vv[c], oacc[i][c]);
            }
        }
    }

    // ---- epilogue: divide by l, write (in place over q rows of this block)
#pragma unroll
    for (int i = 0; i < 4; ++i) {
        float invl = 1.0f / l_run[i];
        float* op = o + ((size_t)(bb * SEQ + qt0 + (sq << 2) + i) * NHEADS + h) * HDIM + (st << 3);
        float4 o0, o1;
        o0.x = oacc[i][0] * invl; o0.y = oacc[i][1] * invl;
        o0.z = oacc[i][2] * invl; o0.w = oacc[i][3] * invl;
        o1.x = oacc[i][4] * invl; o1.y = oacc[i][5] * invl;
        o1.z = oacc[i][6] * invl; o1.w = oacc[i][7] * invl;
        *reinterpret_cast<float4*>(op)     = o0;
        *reinterpret_cast<float4*>(op + 4) = o1;
    }
}

// ---------------------------------------------------------------------------
extern "C" void kernel_launch(void* const* d_in, const int* in_sizes, int n_in,
                              void* d_out, int out_size, void* d_ws, size_t ws_size,
                              hipStream_t stream) {
    const float* x  = (const float*)d_in[0];
    const float* Wq = (const float*)d_in[1];
    const float* bq = (const float*)d_in[2];
    const float* Wk = (const float*)d_in[3];
    const float* bk = (const float*)d_in[4];
    const float* Wv = (const float*)d_in[5];
    const float* bv = (const float*)d_in[6];
    const float* Wo = (const float*)d_in[7];
    const float* bo = (const float*)d_in[8];
    float* out = (float*)d_out;

    float* qbuf = (float*)d_ws;                       // ROWS*DMODEL
    float* kbuf = qbuf + (size_t)ROWS * DMODEL;       // ROWS*KVD
    float* vbuf = kbuf + (size_t)ROWS * KVD;          // ROWS*KVD
    float* sint = vbuf + (size_t)ROWS * KVD;          // SEQ*64
    float* cost = sint + (size_t)SEQ * 64;            // SEQ*64

    // 1. RoPE tables
    rope_table_kernel<<<SEQ * 64 / 256, 256, 0, stream>>>(sint, cost);

    // 2. QKV projections
    sgemm_bias_kernel<<<dim3(DMODEL / GBN, ROWS / GBM), 256, 0, stream>>>(
        x, Wq, bq, qbuf, ROWS, DMODEL, DMODEL);
    sgemm_bias_kernel<<<dim3(KVD / GBN, ROWS / GBM), 256, 0, stream>>>(
        x, Wk, bk, kbuf, ROWS, KVD, DMODEL);
    sgemm_bias_kernel<<<dim3(KVD / GBN, ROWS / GBM), 256, 0, stream>>>(
        x, Wv, bv, vbuf, ROWS, KVD, DMODEL);

    // 3. RoPE
    rope_apply_kernel<<<(ROWS * NHEADS * 64) / 256, 256, 0, stream>>>(qbuf, sint, cost, NHEADS);
    rope_apply_kernel<<<(ROWS * NGROUPS * 64) / 256, 256, 0, stream>>>(kbuf, sint, cost, NGROUPS);

    // 4. attention (writes in place into qbuf)
    attn_kernel<<<dim3(SEQ / 64, NHEADS, BATCH), 256, 0, stream>>>(qbuf, kbuf, vbuf, qbuf);

    // 5. output projection
    sgemm_bias_kernel<<<dim3(DMODEL / GBN, ROWS / GBM), 256, 0, stream>>>(
        qbuf, Wo, bo, out, ROWS, DMODEL, DMODEL);
}

// Round 2
// 472.081 us; speedup vs baseline: 4.6652x; 4.6652x over previous
//
#include <hip/hip_runtime.h>
#include <hip/hip_bf16.h>
#include <hip/hip_fp16.h>
#include <math.h>

#define BATCH   4
#define SEQ     1024
#define DMODEL  2048
#define NHEADS  16
#define NGROUPS 2
#define HDIM    128
#define ROWS    (BATCH * SEQ)      // 4096
#define NQKV    2560               // 2048 q + 256 k + 256 v

typedef short  bf16x8 __attribute__((ext_vector_type(8)));
typedef float  f32x4  __attribute__((ext_vector_type(4)));
typedef _Float16 f16x8 __attribute__((ext_vector_type(8)));

__device__ __forceinline__ unsigned short f2bf(float x) {
    unsigned int u = __float_as_uint(x);
    unsigned int r = (u + 0x7fffu + ((u >> 16) & 1u)) >> 16;
    return (unsigned short)r;
}
__device__ __forceinline__ float bf2f(unsigned short h) {
    return __uint_as_float(((unsigned int)h) << 16);
}

__device__ __forceinline__ void glds16(const void* g, void* s) {
    __builtin_amdgcn_global_load_lds(
        (__attribute__((address_space(1))) void*)g,
        (__attribute__((address_space(3))) void*)s, 16, 0, 0);
}

// ---------------------------------------------------------------------------
// RoPE tables: sin/cos[p][j], p in [0,SEQ), j in [0,64)
// ---------------------------------------------------------------------------
__global__ void rope_table_kernel(float* __restrict__ sin_t, float* __restrict__ cos_t) {
    int idx = blockIdx.x * 256 + threadIdx.x;
    int p = idx >> 6, j = idx & 63;
    float inv = powf(10000.0f, -(float)j * (1.0f / 64.0f));
    float f = (float)p * inv;
    sin_t[idx] = sinf(f);
    cos_t[idx] = cosf(f);
}

// ---------------------------------------------------------------------------
// Split x (fp32 [ROWS][DMODEL]) -> hi/lo bf16, same layout.
// ---------------------------------------------------------------------------
__global__ void split_x_kernel(const float* __restrict__ x,
                               unsigned short* __restrict__ hi,
                               unsigned short* __restrict__ lo) {
    int i = (blockIdx.x * 256 + threadIdx.x) * 4;
    float4 v = *reinterpret_cast<const float4*>(x + i);
    ushort4 h, l;
    h.x = f2bf(v.x); l.x = f2bf(v.x - bf2f(h.x));
    h.y = f2bf(v.y); l.y = f2bf(v.y - bf2f(h.y));
    h.z = f2bf(v.z); l.z = f2bf(v.z - bf2f(h.z));
    h.w = f2bf(v.w); l.w = f2bf(v.w - bf2f(h.w));
    *reinterpret_cast<ushort4*>(hi + i) = h;
    *reinterpret_cast<ushort4*>(lo + i) = l;
}

// ---------------------------------------------------------------------------
// Split + transpose W [K][N] fp32 -> Wt_hi/lo [N][K] bf16 (dst row offset).
// ---------------------------------------------------------------------------
__global__ __launch_bounds__(256)
void split_transpose_kernel(const float* __restrict__ W, int ldw,
                            unsigned short* __restrict__ dhi,
                            unsigned short* __restrict__ dlo,
                            int drow0, int K) {
    __shared__ float tile[64][65];
    int n0 = blockIdx.x * 64, k0 = blockIdx.y * 64;
#pragma unroll
    for (int it = 0; it < 16; ++it) {
        int e = it * 256 + threadIdx.x;
        int r = e >> 6, c = e & 63;
        tile[r][c] = W[(size_t)(k0 + r) * ldw + n0 + c];
    }
    __syncthreads();
#pragma unroll
    for (int it = 0; it < 16; ++it) {
        int e = it * 256 + threadIdx.x;
        int nr = e >> 6, kc = e & 63;
        float v = tile[kc][nr];
        unsigned short h = f2bf(v);
        size_t off = (size_t)(drow0 + n0 + nr) * K + k0 + kc;
        dhi[off] = h;
        dlo[off] = f2bf(v - bf2f(h));
    }
}

// ---------------------------------------------------------------------------
__global__ void bias_cat_kernel(const float* __restrict__ bq, const float* __restrict__ bk,
                                const float* __restrict__ bv, float* __restrict__ bc) {
    int i = blockIdx.x * 256 + threadIdx.x;
    if (i >= NQKV) return;
    bc[i] = (i < 2048) ? bq[i] : ((i < 2304) ? bk[i - 2048] : bv[i - 2304]);
}

// ---------------------------------------------------------------------------
// Split-bf16 GEMM: C[M][N] = (Ahi+Alo)[M][K] @ (Bhi+Blo)^T[N][K] + bias.
// 128x128 tile, BK=32, 256 threads (2x2 waves, 64x64 each), m97 structure.
// 3 MFMAs per fragment pair: hi*hi + hi*lo + lo*hi.
// ---------------------------------------------------------------------------
template<int OUT_HALF>
__global__ __launch_bounds__(256, 2)
void gemm_split_kernel(const unsigned short* __restrict__ Ahi, const unsigned short* __restrict__ Alo,
                       const unsigned short* __restrict__ Bhi, const unsigned short* __restrict__ Blo,
                       const float* __restrict__ bias, void* __restrict__ Cout,
                       int M, int N, int K) {
    __shared__ __align__(16) unsigned short lds[16384];   // 32 KB: 4 tiles [128][32]
    unsigned short* As_h = lds;
    unsigned short* As_l = lds + 4096;
    unsigned short* Bs_h = lds + 8192;
    unsigned short* Bs_l = lds + 12288;

    const int tid  = threadIdx.x;
    const int lane = tid & 63;
    const int w    = tid >> 6;
    const int nbn  = N >> 7;
    const int nwg  = gridDim.x;
    const int cpx  = nwg >> 3;                     // nwg % 8 == 0 for all our grids
    const int bid  = blockIdx.x;
    const int swz  = (bid & 7) * cpx + (bid >> 3); // XCD-aware swizzle (bijective)
    const int row0 = (swz / nbn) << 7;
    const int col0 = (swz % nbn) << 7;
    const int wr   = (w >> 1) << 6;
    const int wc   = (w & 1) << 6;

    const f32x4 fz = {0.f, 0.f, 0.f, 0.f};
    f32x4 acc[4][4];
#pragma unroll
    for (int i = 0; i < 4; ++i)
#pragma unroll
        for (int j = 0; j < 4; ++j) acc[i][j] = fz;

    for (int k0 = 0; k0 < K; k0 += 32) {
        __syncthreads();
#pragma unroll
        for (int it = 0; it < 2; ++it) {
            int chunk = it * 256 + tid;            // 0..511
            int trow  = chunk >> 2;                // 0..127
            int tkc   = (chunk & 3) << 3;          // 0,8,16,24
            size_t aoff = (size_t)(row0 + trow) * K + k0 + tkc;
            size_t boff = (size_t)(col0 + trow) * K + k0 + tkc;
            int ldst = (it * 256 + (tid & 192)) * 16;   // wave-uniform byte base
            glds16(Ahi + aoff, (char*)As_h + ldst);
            glds16(Alo + aoff, (char*)As_l + ldst);
            glds16(Bhi + boff, (char*)Bs_h + ldst);
            glds16(Blo + boff, (char*)Bs_l + ldst);
        }
        __syncthreads();

        bf16x8 ah[4], al[4], bh[4], bl[4];
#pragma unroll
        for (int i = 0; i < 4; ++i) {
            int ar   = wr + i * 16 + (lane & 15);
            int aoff = ar * 64 + ((lane >> 4) << 4);
            ah[i] = *reinterpret_cast<const bf16x8*>((const char*)As_h + aoff);
            al[i] = *reinterpret_cast<const bf16x8*>((const char*)As_l + aoff);
            int br   = wc + i * 16 + (lane & 15);
            int boff = br * 64 + ((lane >> 4) << 4);
            bh[i] = *reinterpret_cast<const bf16x8*>((const char*)Bs_h + boff);
            bl[i] = *reinterpret_cast<const bf16x8*>((const char*)Bs_l + boff);
        }
#pragma unroll
        for (int i = 0; i < 4; ++i)
#pragma unroll
            for (int j = 0; j < 4; ++j) {
                acc[i][j] = __builtin_amdgcn_mfma_f32_16x16x32_bf16(ah[i], bh[j], acc[i][j], 0, 0, 0);
                acc[i][j] = __builtin_amdgcn_mfma_f32_16x16x32_bf16(ah[i], bl[j], acc[i][j], 0, 0, 0);
                acc[i][j] = __builtin_amdgcn_mfma_f32_16x16x32_bf16(al[i], bh[j], acc[i][j], 0, 0, 0);
            }
    }

    float bv4[4];
#pragma unroll
    for (int j = 0; j < 4; ++j) bv4[j] = bias[col0 + wc + j * 16 + (lane & 15)];
#pragma unroll
    for (int i = 0; i < 4; ++i)
#pragma unroll
        for (int j = 0; j < 4; ++j)
#pragma unroll
            for (int r = 0; r < 4; ++r) {
                int grow = row0 + wr + i * 16 + ((lane >> 4) << 2) + r;
                int gcol = col0 + wc + j * 16 + (lane & 15);
                float v = acc[i][j][r] + bv4[j];
                if (OUT_HALF)
                    ((__half*)Cout)[(size_t)grow * N + gcol] = __float2half(v);
                else
                    ((float*)Cout)[(size_t)grow * N + gcol] = v;
            }
}

// ---------------------------------------------------------------------------
// RoPE on q,k from fp16 qkv buffer into attention-friendly fp16 layouts.
// qh: [B][H][S][D] (scaled by 1/sqrt(D));  kh: [B][G][S][D].
// ---------------------------------------------------------------------------
__global__ void rope_qk_kernel(const __half* __restrict__ qkv,
                               const float* __restrict__ sin_t, const float* __restrict__ cos_t,
                               __half* __restrict__ qh, __half* __restrict__ kh) {
    int idx = blockIdx.x * 256 + threadIdx.x;
    int j = idx & 63;
    int t = idx >> 6;
    const int NQ = ROWS * NHEADS;
    if (t < NQ) {
        int row = t >> 4, h = t & 15;
        int b = row >> 10, s = row & 1023;
        float c = cos_t[s * 64 + j], sn = sin_t[s * 64 + j];
        const __half* src = qkv + (size_t)row * NQKV + h * HDIM;
        float x1 = __half2float(src[j]);
        float x2 = __half2float(src[j + 64]);
        const float sc = 0.08838834764831845f;
        __half* dst = qh + ((size_t)(b * NHEADS + h) * SEQ + s) * HDIM;
        dst[j]      = __float2half((x1 * c - x2 * sn) * sc);
        dst[j + 64] = __float2half((x2 * c + x1 * sn) * sc);
    } else {
        int t2 = t - NQ;
        int row = t2 >> 1, g = t2 & 1;
        int b = row >> 10, s = row & 1023;
        float c = cos_t[s * 64 + j], sn = sin_t[s * 64 + j];
        const __half* src = qkv + (size_t)row * NQKV + 2048 + g * HDIM;
        float x1 = __half2float(src[j]);
        float x2 = __half2float(src[j + 64]);
        __half* dst = kh + ((size_t)(b * NGROUPS + g) * SEQ + s) * HDIM;
        dst[j]      = __float2half(x1 * c - x2 * sn);
        dst[j + 64] = __float2half(x2 * c + x1 * sn);
    }
}

// ---------------------------------------------------------------------------
// V transpose: qkv v-slice [B*S][..] -> vt [B][G][D][S] fp16.
// ---------------------------------------------------------------------------
__global__ __launch_bounds__(256)
void transpose_v_kernel(const __half* __restrict__ qkv, __half* __restrict__ vt) {
    __shared__ __half tile[64][66];
    int s0 = blockIdx.x * 64, d0 = blockIdx.y * 64, bg = blockIdx.z;
    int b = bg >> 1, g = bg & 1;
#pragma unroll
    for (int it = 0; it < 16; ++it) {
        int e = it * 256 + threadIdx.x;
        int r = e >> 6, c = e & 63;
        tile[r][c] = qkv[(size_t)(b * SEQ + s0 + r) * NQKV + 2304 + g * HDIM + d0 + c];
    }
    __syncthreads();
#pragma unroll
    for (int it = 0; it < 16; ++it) {
        int e = it * 256 + threadIdx.x;
        int dr = e >> 6, sc = e & 63;
        vt[((size_t)bg * HDIM + d0 + dr) * SEQ + s0 + sc] = tile[sc][dr];
    }
}

// ---------------------------------------------------------------------------
// Flash attention, fp16 MFMA. Grid (SEQ/64, NHEADS, BATCH), 256 thr (4 waves).
// Wave w owns q-rows [w*16, w*16+16). Per 64-KV tile: QK^T (16 MFMA),
// wave-parallel online softmax, P -> wave-private swizzled LDS, PV (16 MFMA).
// All LDS tiles XOR-swizzled; global source pre-swizzled for glds16 (rule 21).
// Output written split to ao_hi/ao_lo bf16 [ROWS][DMODEL].
// ---------------------------------------------------------------------------
__global__ __launch_bounds__(256, 2)
void attn_kernel(const __half* __restrict__ qh, const __half* __restrict__ kh,
                 const __half* __restrict__ vt,
                 unsigned short* __restrict__ ao_hi, unsigned short* __restrict__ ao_lo) {
    __shared__ __align__(16) char smem[57344];
    char* Qs = smem;             // [64 rows][256 B] swizzled
    char* Ks = smem + 16384;     // [64 rows][256 B] swizzled
    char* Vs = smem + 32768;     // [128 rows][128 B] swizzled
    char* Ps = smem + 49152;     // 4 waves x [16 rows][128 B] swizzled

    const int tid = threadIdx.x, lane = tid & 63, w = tid >> 6;
    const int qt0 = blockIdx.x << 6;
    const int h = blockIdx.y, b = blockIdx.z;
    const int g = h >> 3;
    const __half* qbase = qh + ((size_t)(b * NHEADS + h) * SEQ + qt0) * HDIM;
    const __half* kbase = kh + (size_t)(b * NGROUPS + g) * SEQ * HDIM;
    const __half* vbase = vt + (size_t)(b * NGROUPS + g) * HDIM * SEQ;

    // stage Q once (swizzled source chunks)
#pragma unroll
    for (int it = 0; it < 4; ++it) {
        int c = it * 256 + tid;
        int row = c >> 4, jc = c & 15;
        int sj = jc ^ (row & 7);
        glds16((const char*)(qbase + (size_t)row * HDIM) + (sj << 4),
               Qs + (it * 256 + (tid & 192)) * 16);
    }

    float m_run[4] = {-1e30f, -1e30f, -1e30f, -1e30f};
    float l_run[4] = {0.f, 0.f, 0.f, 0.f};
    const f32x4 fz = {0.f, 0.f, 0.f, 0.f};
    f32x4 oacc[8];
#pragma unroll
    for (int i = 0; i < 8; ++i) oacc[i] = fz;

    const int qrow   = w * 16 + (lane & 15);
    const int qroff  = qrow * 256;
    const int qswz   = qrow & 7;
    char* Pw = Ps + w * 2048;
    const int prow   = lane & 15;
    const int pswz   = prow & 7;

    for (int t0 = 0; t0 < SEQ; t0 += 64) {
        __syncthreads();
#pragma unroll
        for (int it = 0; it < 4; ++it) {           // stage K tile
            int c = it * 256 + tid;
            int row = c >> 4, jc = c & 15;
            int sj = jc ^ (row & 7);
            glds16((const char*)(kbase + (size_t)(t0 + row) * HDIM) + (sj << 4),
                   Ks + (it * 256 + (tid & 192)) * 16);
        }
#pragma unroll
        for (int it = 0; it < 4; ++it) {           // stage V^T tile
            int c = it * 256 + tid;
            int d = c >> 3, jc = c & 7;
            int sj = jc ^ (d & 7);
            glds16((const char*)(vbase + (size_t)d * SEQ + t0) + (sj << 4),
                   Vs + (it * 256 + (tid & 192)) * 16);
        }
        __syncthreads();

        // ---- S = Q K^T ----
        f32x4 sacc[4];
#pragma unroll
        for (int i = 0; i < 4; ++i) sacc[i] = fz;
#pragma unroll
        for (int ks = 0; ks < 4; ++ks) {
            int chA = ks * 4 + (lane >> 4);
            f16x8 af = *reinterpret_cast<const f16x8*>(Qs + qroff + ((chA ^ qswz) << 4));
#pragma unroll
            for (int nf = 0; nf < 4; ++nf) {
                int trow = nf * 16 + (lane & 15);
                f16x8 bf = *reinterpret_cast<const f16x8*>(
                    Ks + trow * 256 + (((ks * 4 + (lane >> 4)) ^ (trow & 7)) << 4));
                sacc[nf] = __builtin_amdgcn_mfma_f32_16x16x32_f16(af, bf, sacc[nf], 0, 0, 0);
            }
        }

        // ---- online softmax (rows spread over reg r; stats across 16 lanes) ----
        float mnew[4], scl[4], psum[4];
#pragma unroll
        for (int r = 0; r < 4; ++r) {
            float pm = fmaxf(fmaxf(sacc[0][r], sacc[1][r]), fmaxf(sacc[2][r], sacc[3][r]));
            pm = fmaxf(pm, __shfl_xor(pm, 1, 16));
            pm = fmaxf(pm, __shfl_xor(pm, 2, 16));
            pm = fmaxf(pm, __shfl_xor(pm, 4, 16));
            pm = fmaxf(pm, __shfl_xor(pm, 8, 16));
            mnew[r] = fmaxf(m_run[r], pm);
            scl[r] = __expf(m_run[r] - mnew[r]);
            m_run[r] = mnew[r];
            psum[r] = 0.f;
        }
#pragma unroll
        for (int nf = 0; nf < 4; ++nf)
#pragma unroll
            for (int r = 0; r < 4; ++r) {
                float p = __expf(sacc[nf][r] - mnew[r]);
                sacc[nf][r] = p;
                psum[r] += p;
            }
#pragma unroll
        for (int r = 0; r < 4; ++r) {
            float ps = psum[r];
            ps += __shfl_xor(ps, 1, 16);
            ps += __shfl_xor(ps, 2, 16);
            ps += __shfl_xor(ps, 4, 16);
            ps += __shfl_xor(ps, 8, 16);
            l_run[r] = l_run[r] * scl[r] + ps;
        }
#pragma unroll
        for (int i = 0; i < 8; ++i) {
            f32x4 o = oacc[i];
            o[0] *= scl[0]; o[1] *= scl[1]; o[2] *= scl[2]; o[3] *= scl[3];
            oacc[i] = o;
        }

        // ---- P -> wave-private swizzled LDS (fp16) ----
#pragma unroll
        for (int nf = 0; nf < 4; ++nf)
#pragma unroll
            for (int r = 0; r < 4; ++r) {
                int pr = ((lane >> 4) << 2) + r;
                int pc = nf * 16 + (lane & 15);
                int byte = pr * 128 + ((pc * 2) ^ ((pr & 7) << 4));
                *reinterpret_cast<_Float16*>(Pw + byte) = (_Float16)sacc[nf][r];
            }

        // ---- O += P V ----
#pragma unroll
        for (int ks = 0; ks < 2; ++ks) {
            int chP = ks * 4 + (lane >> 4);
            f16x8 pa = *reinterpret_cast<const f16x8*>(Pw + prow * 128 + ((chP ^ pswz) << 4));
#pragma unroll
            for (int nf = 0; nf < 8; ++nf) {
                int vrow = nf * 16 + (lane & 15);
                f16x8 vf = *reinterpret_cast<const f16x8*>(
                    Vs + vrow * 128 + (((ks * 4 + (lane >> 4)) ^ (vrow & 7)) << 4));
                oacc[nf] = __builtin_amdgcn_mfma_f32_16x16x32_f16(pa, vf, oacc[nf], 0, 0, 0);
            }
        }
    }

    // ---- epilogue: normalize, split to bf16 hi/lo ----
#pragma unroll
    for (int nf = 0; nf < 8; ++nf)
#pragma unroll
        for (int r = 0; r < 4; ++r) {
            int qr  = qt0 + w * 16 + ((lane >> 4) << 2) + r;
            int col = h * HDIM + nf * 16 + (lane & 15);
            float v = oacc[nf][r] / l_run[r];
            unsigned short hb = f2bf(v);
            size_t off = (size_t)(b * SEQ + qr) * DMODEL + col;
            ao_hi[off] = hb;
            ao_lo[off] = f2bf(v - bf2f(hb));
        }
}

// ---------------------------------------------------------------------------
extern "C" void kernel_launch(void* const* d_in, const int* in_sizes, int n_in,
                              void* d_out, int out_size, void* d_ws, size_t ws_size,
                              hipStream_t stream) {
    const float* x  = (const float*)d_in[0];
    const float* Wq = (const float*)d_in[1];
    const float* bq = (const float*)d_in[2];
    const float* Wk = (const float*)d_in[3];
    const float* bk = (const float*)d_in[4];
    const float* Wv = (const float*)d_in[5];
    const float* bv = (const float*)d_in[6];
    const float* Wo = (const float*)d_in[7];
    const float* bo = (const float*)d_in[8];
    float* out = (float*)d_out;

    char* ws = (char*)d_ws;
    unsigned short* xs_hi  = (unsigned short*)(ws);                    // 16.78 MB
    unsigned short* xs_lo  = (unsigned short*)(ws + 16777216);         // 16.78 MB
    unsigned short* wqkv_h = (unsigned short*)(ws + 33554432);         // 10.49 MB  [2560][2048]
    unsigned short* wqkv_l = (unsigned short*)(ws + 44040192);         // 10.49 MB
    unsigned short* wot_h  = (unsigned short*)(ws + 54525952);         //  8.39 MB  [2048][2048]
    unsigned short* wot_l  = (unsigned short*)(ws + 62914560);         //  8.39 MB
    __half*        qkv16   = (__half*)(ws + 71303168);                 // 20.97 MB  [4096][2560]
    __half*        qhb     = (__half*)(ws + 92274688);                 // 16.78 MB  [B][H][S][D]
    __half*        khb     = (__half*)(ws + 109051904);                //  2.10 MB  [B][G][S][D]
    __half*        vtb     = (__half*)(ws + 111149056);                //  2.10 MB  [B][G][D][S]
    float*         sint    = (float*)(ws + 113246208);                 //  0.26 MB
    float*         cost    = (float*)(ws + 113508352);                 //  0.26 MB
    float*         bias_c  = (float*)(ws + 113770496);                 //  10 KB
    // attention output (split bf16) reuses xs_hi/xs_lo (x is dead after QKV GEMM)
    unsigned short* ao_hi = xs_hi;
    unsigned short* ao_lo = xs_lo;

    rope_table_kernel<<<SEQ * 64 / 256, 256, 0, stream>>>(sint, cost);
    split_x_kernel<<<ROWS * DMODEL / 4 / 256, 256, 0, stream>>>(x, xs_hi, xs_lo);
    split_transpose_kernel<<<dim3(32, 32), 256, 0, stream>>>(Wq, DMODEL, wqkv_h, wqkv_l, 0, DMODEL);
    split_transpose_kernel<<<dim3(4, 32),  256, 0, stream>>>(Wk, 256,    wqkv_h, wqkv_l, 2048, DMODEL);
    split_transpose_kernel<<<dim3(4, 32),  256, 0, stream>>>(Wv, 256,    wqkv_h, wqkv_l, 2304, DMODEL);
    split_transpose_kernel<<<dim3(32, 32), 256, 0, stream>>>(Wo, DMODEL, wot_h,  wot_l,  0, DMODEL);
    bias_cat_kernel<<<10, 256, 0, stream>>>(bq, bk, bv, bias_c);

    // QKV projection: [4096][2048] @ [2048][2560] -> fp16 [4096][2560]
    gemm_split_kernel<1><<<(ROWS / 128) * (NQKV / 128), 256, 0, stream>>>(
        xs_hi, xs_lo, wqkv_h, wqkv_l, bias_c, qkv16, ROWS, NQKV, DMODEL);

    rope_qk_kernel<<<(ROWS * (NHEADS + NGROUPS) * 64) / 256, 256, 0, stream>>>(
        qkv16, sint, cost, qhb, khb);
    transpose_v_kernel<<<dim3(SEQ / 64, HDIM / 64, BATCH * NGROUPS), 256, 0, stream>>>(qkv16, vtb);

    attn_kernel<<<dim3(SEQ / 64, NHEADS, BATCH), 256, 0, stream>>>(qhb, khb, vtb, ao_hi, ao_lo);

    // Output projection: [4096][2048] @ [2048][2048] -> fp32 out
    gemm_split_kernel<0><<<(ROWS / 128) * (DMODEL / 128), 256, 0, stream>>>(
        ao_hi, ao_lo, wot_h, wot_l, bo, out, ROWS, DMODEL, DMODEL);
}

// Round 4
// 402.059 us; speedup vs baseline: 5.4777x; 1.1742x over previous
//
#include <hip/hip_runtime.h>
#include <hip/hip_bf16.h>
#include <hip/hip_fp16.h>
#include <math.h>

#define BATCH   4
#define SEQ     1024
#define DMODEL  2048
#define NHEADS  16
#define NGROUPS 2
#define HDIM    128
#define ROWS    (BATCH * SEQ)      // 4096
#define NQKV    2560               // 2048 q + 256 k + 256 v

typedef float    f32x4 __attribute__((ext_vector_type(4)));
typedef _Float16 f16x8 __attribute__((ext_vector_type(8)));

__device__ __forceinline__ void glds16(const void* g, void* s) {
    __builtin_amdgcn_global_load_lds(
        (__attribute__((address_space(1))) void*)g,
        (__attribute__((address_space(3))) void*)s, 16, 0, 0);
}

// ---------------------------------------------------------------------------
// RoPE tables: sin/cos[p][j], p in [0,SEQ), j in [0,64)
// ---------------------------------------------------------------------------
__global__ void rope_table_kernel(float* __restrict__ sin_t, float* __restrict__ cos_t) {
    int idx = blockIdx.x * 256 + threadIdx.x;
    int p = idx >> 6, j = idx & 63;
    float inv = powf(10000.0f, -(float)j * (1.0f / 64.0f));
    float f = (float)p * inv;
    sin_t[idx] = sinf(f);
    cos_t[idx] = cosf(f);
}

// ---------------------------------------------------------------------------
// Split x (fp32 [ROWS][DMODEL]) -> hi/lo fp16, same layout. 8 elems/thread.
// ---------------------------------------------------------------------------
__global__ void split_x_kernel(const float* __restrict__ x,
                               _Float16* __restrict__ hi, _Float16* __restrict__ lo) {
    int i = (blockIdx.x * 256 + threadIdx.x) * 8;
    float v[8];
    *reinterpret_cast<float4*>(&v[0]) = *reinterpret_cast<const float4*>(x + i);
    *reinterpret_cast<float4*>(&v[4]) = *reinterpret_cast<const float4*>(x + i + 4);
    f16x8 h, l;
#pragma unroll
    for (int j = 0; j < 8; ++j) {
        h[j] = (_Float16)v[j];
        l[j] = (_Float16)(v[j] - (float)h[j]);
    }
    *reinterpret_cast<f16x8*>(hi + i) = h;
    *reinterpret_cast<f16x8*>(lo + i) = l;
}

// ---------------------------------------------------------------------------
// Transpose W [K][N] fp32 -> fp16 [N][K] (dst row offset drow0).
// ---------------------------------------------------------------------------
__global__ __launch_bounds__(256)
void transpose_w_kernel(const float* __restrict__ W, int ldw,
                        _Float16* __restrict__ dst, int drow0, int K) {
    __shared__ float tile[64][65];
    int n0 = blockIdx.x * 64, k0 = blockIdx.y * 64;
#pragma unroll
    for (int it = 0; it < 16; ++it) {
        int e = it * 256 + threadIdx.x;
        int r = e >> 6, c = e & 63;
        tile[r][c] = W[(size_t)(k0 + r) * ldw + n0 + c];
    }
    __syncthreads();
#pragma unroll
    for (int it = 0; it < 16; ++it) {
        int e = it * 256 + threadIdx.x;
        int nr = e >> 6, kc = e & 63;
        dst[(size_t)(drow0 + n0 + nr) * K + k0 + kc] = (_Float16)tile[kc][nr];
    }
}

// ---------------------------------------------------------------------------
__global__ void bias_cat_kernel(const float* __restrict__ bq, const float* __restrict__ bk,
                                const float* __restrict__ bv, float* __restrict__ bc) {
    int i = blockIdx.x * 256 + threadIdx.x;
    if (i >= NQKV) return;
    bc[i] = (i < 2048) ? bq[i] : ((i < 2304) ? bk[i - 2048] : bv[i - 2304]);
}

// ---------------------------------------------------------------------------
// Split-fp16 GEMM: C[M][N] = (Ah+Al)[M][K] @ Bt^T[N][K] + bias.
// 128x128 tile, BK=32, 256 threads (2x2 waves, 64x64 each), m97 structure.
// 2 MFMAs per fragment pair: Ah*B + Al*B.
// ---------------------------------------------------------------------------
template<int OUT_HALF>
__global__ __launch_bounds__(256, 3)
void gemm_fp16_kernel(const _Float16* __restrict__ Ah, const _Float16* __restrict__ Al,
                      const _Float16* __restrict__ Bt, const float* __restrict__ bias,
                      void* __restrict__ Cout, int M, int N, int K) {
    __shared__ __align__(16) _Float16 lds[12288];   // 24 KB: 3 tiles [128][32]
    _Float16* As_h = lds;
    _Float16* As_l = lds + 4096;
    _Float16* Bs   = lds + 8192;

    const int tid  = threadIdx.x;
    const int lane = tid & 63;
    const int w    = tid >> 6;
    const int nbn  = N >> 7;
    const int nwg  = gridDim.x;
    const int cpx  = nwg >> 3;                     // nwg % 8 == 0 for our grids
    const int bid  = blockIdx.x;
    const int swz  = (bid & 7) * cpx + (bid >> 3); // XCD-aware swizzle (bijective)
    const int row0 = (swz / nbn) << 7;
    const int col0 = (swz % nbn) << 7;
    const int wr   = (w >> 1) << 6;
    const int wc   = (w & 1) << 6;

    const f32x4 fz = {0.f, 0.f, 0.f, 0.f};
    f32x4 acc[4][4];
#pragma unroll
    for (int i = 0; i < 4; ++i)
#pragma unroll
        for (int j = 0; j < 4; ++j) acc[i][j] = fz;

    for (int k0 = 0; k0 < K; k0 += 32) {
        __syncthreads();
#pragma unroll
        for (int it = 0; it < 2; ++it) {
            int chunk = it * 256 + tid;            // 0..511
            int trow  = chunk >> 2;                // 0..127
            int tkc   = (chunk & 3) << 3;          // 0,8,16,24
            size_t aoff = (size_t)(row0 + trow) * K + k0 + tkc;
            size_t boff = (size_t)(col0 + trow) * K + k0 + tkc;
            int ldst = (it * 256 + (tid & 192)) * 16;   // wave-uniform byte base
            glds16(Ah + aoff, (char*)As_h + ldst);
            glds16(Al + aoff, (char*)As_l + ldst);
            glds16(Bt + boff, (char*)Bs   + ldst);
        }
        __syncthreads();

        f16x8 ah[4], al[4], bb[4];
#pragma unroll
        for (int i = 0; i < 4; ++i) {
            int aoff = (wr + i * 16 + (lane & 15)) * 64 + ((lane >> 4) << 4);
            ah[i] = *reinterpret_cast<const f16x8*>((const char*)As_h + aoff);
            al[i] = *reinterpret_cast<const f16x8*>((const char*)As_l + aoff);
            int boff = (wc + i * 16 + (lane & 15)) * 64 + ((lane >> 4) << 4);
            bb[i] = *reinterpret_cast<const f16x8*>((const char*)Bs + boff);
        }
#pragma unroll
        for (int i = 0; i < 4; ++i)
#pragma unroll
            for (int j = 0; j < 4; ++j) {
                acc[i][j] = __builtin_amdgcn_mfma_f32_16x16x32_f16(ah[i], bb[j], acc[i][j], 0, 0, 0);
                acc[i][j] = __builtin_amdgcn_mfma_f32_16x16x32_f16(al[i], bb[j], acc[i][j], 0, 0, 0);
            }
    }

    float bv4[4];
#pragma unroll
    for (int j = 0; j < 4; ++j) bv4[j] = bias[col0 + wc + j * 16 + (lane & 15)];
#pragma unroll
    for (int i = 0; i < 4; ++i)
#pragma unroll
        for (int j = 0; j < 4; ++j)
#pragma unroll
            for (int r = 0; r < 4; ++r) {
                int grow = row0 + wr + i * 16 + ((lane >> 4) << 2) + r;
                int gcol = col0 + wc + j * 16 + (lane & 15);
                float v = acc[i][j][r] + bv4[j];
                if (OUT_HALF)
                    ((_Float16*)Cout)[(size_t)grow * N + gcol] = (_Float16)v;
                else
                    ((float*)Cout)[(size_t)grow * N + gcol] = v;
            }
}

// ---------------------------------------------------------------------------
// RoPE on q,k from fp16 qkv buffer (vectorized, 8 j's per thread).
// qh: [B][H][S][D] (scaled by 1/sqrt(D));  kh: [B][G][S][D].
// ---------------------------------------------------------------------------
__global__ void rope_qk_kernel(const _Float16* __restrict__ qkv,
                               const float* __restrict__ sin_t, const float* __restrict__ cos_t,
                               _Float16* __restrict__ qh, _Float16* __restrict__ kh) {
    int idx = blockIdx.x * 256 + threadIdx.x;
    int jc = idx & 7, t = idx >> 3;
    int j0 = jc * 8;
    const int NQ = ROWS * NHEADS;
    const _Float16* src;
    _Float16* dst;
    int s;
    float qsc;
    if (t < NQ) {
        int row = t >> 4, h = t & 15;
        int b = row >> 10; s = row & 1023;
        src = qkv + (size_t)row * NQKV + h * HDIM;
        dst = qh + ((size_t)(b * NHEADS + h) * SEQ + s) * HDIM;
        qsc = 0.08838834764831845f;
    } else {
        int t2 = t - NQ;
        int row = t2 >> 1, g = t2 & 1;
        int b = row >> 10; s = row & 1023;
        src = qkv + (size_t)row * NQKV + 2048 + g * HDIM;
        dst = kh + ((size_t)(b * NGROUPS + g) * SEQ + s) * HDIM;
        qsc = 1.0f;
    }
    f16x8 x1 = *reinterpret_cast<const f16x8*>(src + j0);
    f16x8 x2 = *reinterpret_cast<const f16x8*>(src + j0 + 64);
    float cc[8], ss[8];
    *reinterpret_cast<float4*>(&cc[0]) = *reinterpret_cast<const float4*>(cos_t + s * 64 + j0);
    *reinterpret_cast<float4*>(&cc[4]) = *reinterpret_cast<const float4*>(cos_t + s * 64 + j0 + 4);
    *reinterpret_cast<float4*>(&ss[0]) = *reinterpret_cast<const float4*>(sin_t + s * 64 + j0);
    *reinterpret_cast<float4*>(&ss[4]) = *reinterpret_cast<const float4*>(sin_t + s * 64 + j0 + 4);
    f16x8 o1, o2;
#pragma unroll
    for (int j = 0; j < 8; ++j) {
        float f1 = (float)x1[j], f2 = (float)x2[j];
        o1[j] = (_Float16)((f1 * cc[j] - f2 * ss[j]) * qsc);
        o2[j] = (_Float16)((f2 * cc[j] + f1 * ss[j]) * qsc);
    }
    *reinterpret_cast<f16x8*>(dst + j0)      = o1;
    *reinterpret_cast<f16x8*>(dst + j0 + 64) = o2;
}

// ---------------------------------------------------------------------------
// V transpose: qkv v-slice -> vt [B][G][D][S] fp16 (vectorized).
// ---------------------------------------------------------------------------
__global__ __launch_bounds__(256)
void transpose_v_kernel(const _Float16* __restrict__ qkv, _Float16* __restrict__ vt) {
    __shared__ _Float16 tile[64][72];
    int s0 = blockIdx.x * 64, d0 = blockIdx.y * 64, bg = blockIdx.z;
    int b = bg >> 1, g = bg & 1;
#pragma unroll
    for (int it = 0; it < 2; ++it) {
        int c = it * 256 + threadIdx.x;
        int r = c >> 3, cc = (c & 7) * 8;
        f16x8 v = *reinterpret_cast<const f16x8*>(
            qkv + (size_t)(b * SEQ + s0 + r) * NQKV + 2304 + g * HDIM + d0 + cc);
#pragma unroll
        for (int j = 0; j < 8; ++j) tile[r][cc + j] = v[j];
    }
    __syncthreads();
#pragma unroll
    for (int it = 0; it < 2; ++it) {
        int c = it * 256 + threadIdx.x;
        int dr = c >> 3, sc = (c & 7) * 8;
        f16x8 o;
#pragma unroll
        for (int j = 0; j < 8; ++j) o[j] = tile[sc + j][dr];
        *reinterpret_cast<f16x8*>(vt + ((size_t)bg * HDIM + d0 + dr) * SEQ + s0 + sc) = o;
    }
}

// ---------------------------------------------------------------------------
// Flash attention, fp16 MFMA. Grid (SEQ/64, NHEADS, BATCH), 256 thr (4 waves).
// Output written split (fp16 hi/lo) for the O-projection.
// ---------------------------------------------------------------------------
__global__ __launch_bounds__(256, 2)
void attn_kernel(const _Float16* __restrict__ qh, const _Float16* __restrict__ kh,
                 const _Float16* __restrict__ vt,
                 _Float16* __restrict__ ao_h, _Float16* __restrict__ ao_l) {
    __shared__ __align__(16) char smem[57344];
    char* Qs = smem;             // [64 rows][256 B] swizzled
    char* Ks = smem + 16384;     // [64 rows][256 B] swizzled
    char* Vs = smem + 32768;     // [128 rows][128 B] swizzled
    char* Ps = smem + 49152;     // 4 waves x [16 rows][128 B] swizzled

    const int tid = threadIdx.x, lane = tid & 63, w = tid >> 6;
    const int qt0 = blockIdx.x << 6;
    const int h = blockIdx.y, b = blockIdx.z;
    const int g = h >> 3;
    const _Float16* qbase = qh + ((size_t)(b * NHEADS + h) * SEQ + qt0) * HDIM;
    const _Float16* kbase = kh + (size_t)(b * NGROUPS + g) * SEQ * HDIM;
    const _Float16* vbase = vt + (size_t)(b * NGROUPS + g) * HDIM * SEQ;

#pragma unroll
    for (int it = 0; it < 4; ++it) {
        int c = it * 256 + tid;
        int row = c >> 4, jc = c & 15;
        int sj = jc ^ (row & 7);
        glds16((const char*)(qbase + (size_t)row * HDIM) + (sj << 4),
               Qs + (it * 256 + (tid & 192)) * 16);
    }

    float m_run[4] = {-1e30f, -1e30f, -1e30f, -1e30f};
    float l_run[4] = {0.f, 0.f, 0.f, 0.f};
    const f32x4 fz = {0.f, 0.f, 0.f, 0.f};
    f32x4 oacc[8];
#pragma unroll
    for (int i = 0; i < 8; ++i) oacc[i] = fz;

    const int qrow  = w * 16 + (lane & 15);
    const int qroff = qrow * 256;
    const int qswz  = qrow & 7;
    char* Pw = Ps + w * 2048;
    const int prow  = lane & 15;
    const int pswz  = prow & 7;

    for (int t0 = 0; t0 < SEQ; t0 += 64) {
        __syncthreads();
#pragma unroll
        for (int it = 0; it < 4; ++it) {           // stage K tile
            int c = it * 256 + tid;
            int row = c >> 4, jc = c & 15;
            int sj = jc ^ (row & 7);
            glds16((const char*)(kbase + (size_t)(t0 + row) * HDIM) + (sj << 4),
                   Ks + (it * 256 + (tid & 192)) * 16);
        }
#pragma unroll
        for (int it = 0; it < 4; ++it) {           // stage V^T tile
            int c = it * 256 + tid;
            int d = c >> 3, jc = c & 7;
            int sj = jc ^ (d & 7);
            glds16((const char*)(vbase + (size_t)d * SEQ + t0) + (sj << 4),
                   Vs + (it * 256 + (tid & 192)) * 16);
        }
        __syncthreads();

        // ---- S = Q K^T ----
        f32x4 sacc[4];
#pragma unroll
        for (int i = 0; i < 4; ++i) sacc[i] = fz;
#pragma unroll
        for (int ks = 0; ks < 4; ++ks) {
            int chA = ks * 4 + (lane >> 4);
            f16x8 af = *reinterpret_cast<const f16x8*>(Qs + qroff + ((chA ^ qswz) << 4));
#pragma unroll
            for (int nf = 0; nf < 4; ++nf) {
                int trow = nf * 16 + (lane & 15);
                f16x8 bf = *reinterpret_cast<const f16x8*>(
                    Ks + trow * 256 + (((ks * 4 + (lane >> 4)) ^ (trow & 7)) << 4));
                sacc[nf] = __builtin_amdgcn_mfma_f32_16x16x32_f16(af, bf, sacc[nf], 0, 0, 0);
            }
        }

        // ---- online softmax ----
        float mnew[4], scl[4], psum[4];
#pragma unroll
        for (int r = 0; r < 4; ++r) {
            float pm = fmaxf(fmaxf(sacc[0][r], sacc[1][r]), fmaxf(sacc[2][r], sacc[3][r]));
            pm = fmaxf(pm, __shfl_xor(pm, 1, 16));
            pm = fmaxf(pm, __shfl_xor(pm, 2, 16));
            pm = fmaxf(pm, __shfl_xor(pm, 4, 16));
            pm = fmaxf(pm, __shfl_xor(pm, 8, 16));
            mnew[r] = fmaxf(m_run[r], pm);
            scl[r] = __expf(m_run[r] - mnew[r]);
            m_run[r] = mnew[r];
            psum[r] = 0.f;
        }
#pragma unroll
        for (int nf = 0; nf < 4; ++nf)
#pragma unroll
            for (int r = 0; r < 4; ++r) {
                float p = __expf(sacc[nf][r] - mnew[r]);
                sacc[nf][r] = p;
                psum[r] += p;
            }
#pragma unroll
        for (int r = 0; r < 4; ++r) {
            float ps = psum[r];
            ps += __shfl_xor(ps, 1, 16);
            ps += __shfl_xor(ps, 2, 16);
            ps += __shfl_xor(ps, 4, 16);
            ps += __shfl_xor(ps, 8, 16);
            l_run[r] = l_run[r] * scl[r] + ps;
        }
#pragma unroll
        for (int i = 0; i < 8; ++i) {
            f32x4 o = oacc[i];
            o[0] *= scl[0]; o[1] *= scl[1]; o[2] *= scl[2]; o[3] *= scl[3];
            oacc[i] = o;
        }

        // ---- P -> wave-private swizzled LDS (fp16) ----
#pragma unroll
        for (int nf = 0; nf < 4; ++nf)
#pragma unroll
            for (int r = 0; r < 4; ++r) {
                int pr = ((lane >> 4) << 2) + r;
                int pc = nf * 16 + (lane & 15);
                int byte = pr * 128 + ((pc * 2) ^ ((pr & 7) << 4));
                *reinterpret_cast<_Float16*>(Pw + byte) = (_Float16)sacc[nf][r];
            }

        // ---- O += P V ----
#pragma unroll
        for (int ks = 0; ks < 2; ++ks) {
            int chP = ks * 4 + (lane >> 4);
            f16x8 pa = *reinterpret_cast<const f16x8*>(Pw + prow * 128 + ((chP ^ pswz) << 4));
#pragma unroll
            for (int nf = 0; nf < 8; ++nf) {
                int vrow = nf * 16 + (lane & 15);
                f16x8 vf = *reinterpret_cast<const f16x8*>(
                    Vs + vrow * 128 + (((ks * 4 + (lane >> 4)) ^ (vrow & 7)) << 4));
                oacc[nf] = __builtin_amdgcn_mfma_f32_16x16x32_f16(pa, vf, oacc[nf], 0, 0, 0);
            }
        }
    }

    // ---- epilogue: normalize, split to fp16 hi/lo ----
#pragma unroll
    for (int nf = 0; nf < 8; ++nf)
#pragma unroll
        for (int r = 0; r < 4; ++r) {
            int qr  = qt0 + w * 16 + ((lane >> 4) << 2) + r;
            int col = h * HDIM + nf * 16 + (lane & 15);
            float v = oacc[nf][r] / l_run[r];
            _Float16 hb = (_Float16)v;
            size_t off = (size_t)(b * SEQ + qr) * DMODEL + col;
            ao_h[off] = hb;
            ao_l[off] = (_Float16)(v - (float)hb);
        }
}

// ---------------------------------------------------------------------------
extern "C" void kernel_launch(void* const* d_in, const int* in_sizes, int n_in,
                              void* d_out, int out_size, void* d_ws, size_t ws_size,
                              hipStream_t stream) {
    const float* x  = (const float*)d_in[0];
    const float* Wq = (const float*)d_in[1];
    const float* bq = (const float*)d_in[2];
    const float* Wk = (const float*)d_in[3];
    const float* bk = (const float*)d_in[4];
    const float* Wv = (const float*)d_in[5];
    const float* bv = (const float*)d_in[6];
    const float* Wo = (const float*)d_in[7];
    const float* bo = (const float*)d_in[8];
    float* out = (float*)d_out;

    char* ws = (char*)d_ws;
    _Float16* xs_h   = (_Float16*)(ws);                    // 16.78 MB [4096][2048]
    _Float16* xs_l   = (_Float16*)(ws + 16777216);         // 16.78 MB
    _Float16* wqkv16 = (_Float16*)(ws + 33554432);         // 10.49 MB [2560][2048]
    _Float16* wot16  = (_Float16*)(ws + 44040192);         //  8.39 MB [2048][2048]
    _Float16* qkv16  = (_Float16*)(ws + 52428800);         // 20.97 MB [4096][2560]
    _Float16* qhb    = (_Float16*)(ws + 73400320);         // 16.78 MB [B][H][S][D]
    _Float16* khb    = (_Float16*)(ws + 90177536);         //  2.10 MB [B][G][S][D]
    _Float16* vtb    = (_Float16*)(ws + 92274688);         //  2.10 MB [B][G][D][S]
    float*    sint   = (float*)(ws + 94371840);            //  0.26 MB
    float*    cost   = (float*)(ws + 94633984);            //  0.26 MB
    float*    bias_c = (float*)(ws + 94896128);            //  10 KB
    // attention output (split fp16) reuses xs_h/xs_l (x dead after QKV GEMM)
    _Float16* ao_h = xs_h;
    _Float16* ao_l = xs_l;

    rope_table_kernel<<<SEQ * 64 / 256, 256, 0, stream>>>(sint, cost);
    split_x_kernel<<<ROWS * DMODEL / 8 / 256, 256, 0, stream>>>(x, xs_h, xs_l);
    transpose_w_kernel<<<dim3(32, 32), 256, 0, stream>>>(Wq, DMODEL, wqkv16, 0, DMODEL);
    transpose_w_kernel<<<dim3(4, 32),  256, 0, stream>>>(Wk, 256,    wqkv16, 2048, DMODEL);
    transpose_w_kernel<<<dim3(4, 32),  256, 0, stream>>>(Wv, 256,    wqkv16, 2304, DMODEL);
    transpose_w_kernel<<<dim3(32, 32), 256, 0, stream>>>(Wo, DMODEL, wot16,  0, DMODEL);
    bias_cat_kernel<<<10, 256, 0, stream>>>(bq, bk, bv, bias_c);

    // QKV projection: [4096][2048] @ [2048][2560] -> fp16 [4096][2560]
    gemm_fp16_kernel<1><<<(ROWS / 128) * (NQKV / 128), 256, 0, stream>>>(
        xs_h, xs_l, wqkv16, bias_c, qkv16, ROWS, NQKV, DMODEL);

    rope_qk_kernel<<<(ROWS * (NHEADS + NGROUPS) * 8) / 256, 256, 0, stream>>>(
        qkv16, sint, cost, qhb, khb);
    transpose_v_kernel<<<dim3(SEQ / 64, HDIM / 64, BATCH * NGROUPS), 256, 0, stream>>>(qkv16, vtb);

    attn_kernel<<<dim3(SEQ / 64, NHEADS, BATCH), 256, 0, stream>>>(qhb, khb, vtb, ao_h, ao_l);

    // Output projection: [4096][2048] @ [2048][2048] -> fp32 out
    gemm_fp16_kernel<0><<<(ROWS / 128) * (DMODEL / 128), 256, 0, stream>>>(
        ao_h, ao_l, wot16, bo, out, ROWS, DMODEL, DMODEL);
}

// Round 5
// 324.944 us; speedup vs baseline: 6.7777x; 1.2373x over previous
//
#include <hip/hip_runtime.h>
#include <hip/hip_bf16.h>
#include <hip/hip_fp16.h>
#include <math.h>

#define BATCH   4
#define SEQ     1024
#define DMODEL  2048
#define NHEADS  16
#define NGROUPS 2
#define HDIM    128
#define ROWS    (BATCH * SEQ)      // 4096
#define NQKV    2560               // 2048 q + 256 k + 256 v

typedef float    f32x4 __attribute__((ext_vector_type(4)));
typedef _Float16 f16x8 __attribute__((ext_vector_type(8)));

__device__ __forceinline__ void glds16(const void* g, void* s) {
    __builtin_amdgcn_global_load_lds(
        (__attribute__((address_space(1))) void*)g,
        (__attribute__((address_space(3))) void*)s, 16, 0, 0);
}

// ---------------------------------------------------------------------------
// RoPE tables: sin/cos[p][j], p in [0,SEQ), j in [0,64)
// ---------------------------------------------------------------------------
__global__ void rope_table_kernel(float* __restrict__ sin_t, float* __restrict__ cos_t) {
    int idx = blockIdx.x * 256 + threadIdx.x;
    int p = idx >> 6, j = idx & 63;
    float inv = powf(10000.0f, -(float)j * (1.0f / 64.0f));
    float f = (float)p * inv;
    sin_t[idx] = sinf(f);
    cos_t[idx] = cosf(f);
}

// ---------------------------------------------------------------------------
// Convert x fp32 -> fp16, 8 elems/thread.
// ---------------------------------------------------------------------------
__global__ void convert_x_kernel(const float* __restrict__ x, _Float16* __restrict__ xo) {
    int i = (blockIdx.x * 256 + threadIdx.x) * 8;
    float v[8];
    *reinterpret_cast<float4*>(&v[0]) = *reinterpret_cast<const float4*>(x + i);
    *reinterpret_cast<float4*>(&v[4]) = *reinterpret_cast<const float4*>(x + i + 4);
    f16x8 h;
#pragma unroll
    for (int j = 0; j < 8; ++j) h[j] = (_Float16)v[j];
    *reinterpret_cast<f16x8*>(xo + i) = h;
}

// ---------------------------------------------------------------------------
// Transpose W [K][N] fp32 -> fp16 [N][K] (dst row offset drow0).
// ---------------------------------------------------------------------------
__global__ __launch_bounds__(256)
void transpose_w_kernel(const float* __restrict__ W, int ldw,
                        _Float16* __restrict__ dst, int drow0, int K) {
    __shared__ float tile[64][65];
    int n0 = blockIdx.x * 64, k0 = blockIdx.y * 64;
#pragma unroll
    for (int it = 0; it < 16; ++it) {
        int e = it * 256 + threadIdx.x;
        int r = e >> 6, c = e & 63;
        tile[r][c] = W[(size_t)(k0 + r) * ldw + n0 + c];
    }
    __syncthreads();
#pragma unroll
    for (int it = 0; it < 16; ++it) {
        int e = it * 256 + threadIdx.x;
        int nr = e >> 6, kc = e & 63;
        dst[(size_t)(drow0 + n0 + nr) * K + k0 + kc] = (_Float16)tile[kc][nr];
    }
}

// ---------------------------------------------------------------------------
__global__ void bias_cat_kernel(const float* __restrict__ bq, const float* __restrict__ bk,
                                const float* __restrict__ bv, float* __restrict__ bc) {
    int i = blockIdx.x * 256 + threadIdx.x;
    if (i >= NQKV) return;
    bc[i] = (i < 2048) ? bq[i] : ((i < 2304) ? bk[i - 2048] : bv[i - 2304]);
}

// ---------------------------------------------------------------------------
// fp16 GEMM: C[M][N] = A[M][K] @ Bt^T[N][K] + bias.
// 128x128 tile, BK=64, 256 threads (2x2 waves, 64x64 each).
// LDS rows are 128 B; XOR-swizzle (slot ^ row&7) on both stage-source and
// ds_read (rule 21) -> ~2-way conflicts (free).
// ---------------------------------------------------------------------------
template<int OUT_HALF>
__global__ __launch_bounds__(256, 3)
void gemm_fp16_kernel(const _Float16* __restrict__ A, const _Float16* __restrict__ Bt,
                      const float* __restrict__ bias, void* __restrict__ Cout,
                      int M, int N, int K) {
    __shared__ __align__(16) _Float16 lds[16384];   // 32 KB: A [128][64], B [128][64]
    _Float16* As = lds;
    _Float16* Bs = lds + 8192;

    const int tid  = threadIdx.x;
    const int lane = tid & 63;
    const int w    = tid >> 6;
    const int nbn  = N >> 7;
    const int nwg  = gridDim.x;
    const int cpx  = nwg >> 3;                     // nwg % 8 == 0 for our grids
    const int bid  = blockIdx.x;
    const int swz  = (bid & 7) * cpx + (bid >> 3); // XCD-aware swizzle (bijective)
    const int row0 = (swz / nbn) << 7;
    const int col0 = (swz % nbn) << 7;
    const int wr   = (w >> 1) << 6;
    const int wc   = (w & 1) << 6;

    const f32x4 fz = {0.f, 0.f, 0.f, 0.f};
    f32x4 acc[4][4];
#pragma unroll
    for (int i = 0; i < 4; ++i)
#pragma unroll
        for (int j = 0; j < 4; ++j) acc[i][j] = fz;

    for (int k0 = 0; k0 < K; k0 += 64) {
        __syncthreads();
#pragma unroll
        for (int it = 0; it < 4; ++it) {
            int chunk = it * 256 + tid;            // 0..1023
            int trow  = chunk >> 3;                // 0..127
            int jp    = chunk & 7;                 // dst 16B slot in row
            int j     = jp ^ (trow & 7);           // pre-swizzled source slot
            size_t aoff = (size_t)(row0 + trow) * K + k0 + j * 8;
            size_t boff = (size_t)(col0 + trow) * K + k0 + j * 8;
            int ldst = (it * 256 + (tid & 192)) * 16;   // wave-uniform byte base
            glds16(A  + aoff, (char*)As + ldst);
            glds16(Bt + boff, (char*)Bs + ldst);
        }
        __syncthreads();

#pragma unroll
        for (int ks = 0; ks < 2; ++ks) {
            f16x8 a4[4], b4[4];
            int ja = ks * 4 + (lane >> 4);
#pragma unroll
            for (int i = 0; i < 4; ++i) {
                int ar = wr + i * 16 + (lane & 15);
                a4[i] = *reinterpret_cast<const f16x8*>(
                    (const char*)As + ar * 128 + ((ja ^ (ar & 7)) << 4));
                int br = wc + i * 16 + (lane & 15);
                b4[i] = *reinterpret_cast<const f16x8*>(
                    (const char*)Bs + br * 128 + ((ja ^ (br & 7)) << 4));
            }
#pragma unroll
            for (int i = 0; i < 4; ++i)
#pragma unroll
                for (int j = 0; j < 4; ++j)
                    acc[i][j] = __builtin_amdgcn_mfma_f32_16x16x32_f16(a4[i], b4[j], acc[i][j], 0, 0, 0);
        }
    }

    float bv4[4];
#pragma unroll
    for (int j = 0; j < 4; ++j) bv4[j] = bias[col0 + wc + j * 16 + (lane & 15)];
#pragma unroll
    for (int i = 0; i < 4; ++i)
#pragma unroll
        for (int j = 0; j < 4; ++j)
#pragma unroll
            for (int r = 0; r < 4; ++r) {
                int grow = row0 + wr + i * 16 + ((lane >> 4) << 2) + r;
                int gcol = col0 + wc + j * 16 + (lane & 15);
                float v = acc[i][j][r] + bv4[j];
                if (OUT_HALF)
                    ((_Float16*)Cout)[(size_t)grow * N + gcol] = (_Float16)v;
                else
                    ((float*)Cout)[(size_t)grow * N + gcol] = v;
            }
}

// ---------------------------------------------------------------------------
// RoPE on q,k from fp16 qkv buffer (vectorized, 8 j's per thread).
// qh: [B][H][S][D] (scaled by 1/sqrt(D));  kh: [B][G][S][D].
// ---------------------------------------------------------------------------
__global__ void rope_qk_kernel(const _Float16* __restrict__ qkv,
                               const float* __restrict__ sin_t, const float* __restrict__ cos_t,
                               _Float16* __restrict__ qh, _Float16* __restrict__ kh) {
    int idx = blockIdx.x * 256 + threadIdx.x;
    int jc = idx & 7, t = idx >> 3;
    int j0 = jc * 8;
    const int NQ = ROWS * NHEADS;
    const _Float16* src;
    _Float16* dst;
    int s;
    float qsc;
    if (t < NQ) {
        int row = t >> 4, h = t & 15;
        int b = row >> 10; s = row & 1023;
        src = qkv + (size_t)row * NQKV + h * HDIM;
        dst = qh + ((size_t)(b * NHEADS + h) * SEQ + s) * HDIM;
        qsc = 0.08838834764831845f;
    } else {
        int t2 = t - NQ;
        int row = t2 >> 1, g = t2 & 1;
        int b = row >> 10; s = row & 1023;
        src = qkv + (size_t)row * NQKV + 2048 + g * HDIM;
        dst = kh + ((size_t)(b * NGROUPS + g) * SEQ + s) * HDIM;
        qsc = 1.0f;
    }
    f16x8 x1 = *reinterpret_cast<const f16x8*>(src + j0);
    f16x8 x2 = *reinterpret_cast<const f16x8*>(src + j0 + 64);
    float cc[8], ss[8];
    *reinterpret_cast<float4*>(&cc[0]) = *reinterpret_cast<const float4*>(cos_t + s * 64 + j0);
    *reinterpret_cast<float4*>(&cc[4]) = *reinterpret_cast<const float4*>(cos_t + s * 64 + j0 + 4);
    *reinterpret_cast<float4*>(&ss[0]) = *reinterpret_cast<const float4*>(sin_t + s * 64 + j0);
    *reinterpret_cast<float4*>(&ss[4]) = *reinterpret_cast<const float4*>(sin_t + s * 64 + j0 + 4);
    f16x8 o1, o2;
#pragma unroll
    for (int j = 0; j < 8; ++j) {
        float f1 = (float)x1[j], f2 = (float)x2[j];
        o1[j] = (_Float16)((f1 * cc[j] - f2 * ss[j]) * qsc);
        o2[j] = (_Float16)((f2 * cc[j] + f1 * ss[j]) * qsc);
    }
    *reinterpret_cast<f16x8*>(dst + j0)      = o1;
    *reinterpret_cast<f16x8*>(dst + j0 + 64) = o2;
}

// ---------------------------------------------------------------------------
// V transpose: qkv v-slice -> vt [B][G][D][S] fp16 (vectorized).
// ---------------------------------------------------------------------------
__global__ __launch_bounds__(256)
void transpose_v_kernel(const _Float16* __restrict__ qkv, _Float16* __restrict__ vt) {
    __shared__ _Float16 tile[64][72];
    int s0 = blockIdx.x * 64, d0 = blockIdx.y * 64, bg = blockIdx.z;
    int b = bg >> 1, g = bg & 1;
#pragma unroll
    for (int it = 0; it < 2; ++it) {
        int c = it * 256 + threadIdx.x;
        int r = c >> 3, cc = (c & 7) * 8;
        f16x8 v = *reinterpret_cast<const f16x8*>(
            qkv + (size_t)(b * SEQ + s0 + r) * NQKV + 2304 + g * HDIM + d0 + cc);
#pragma unroll
        for (int j = 0; j < 8; ++j) tile[r][cc + j] = v[j];
    }
    __syncthreads();
#pragma unroll
    for (int it = 0; it < 2; ++it) {
        int c = it * 256 + threadIdx.x;
        int dr = c >> 3, sc = (c & 7) * 8;
        f16x8 o;
#pragma unroll
        for (int j = 0; j < 8; ++j) o[j] = tile[sc + j][dr];
        *reinterpret_cast<f16x8*>(vt + ((size_t)bg * HDIM + d0 + dr) * SEQ + s0 + sc) = o;
    }
}

// ---------------------------------------------------------------------------
// Flash attention, fp16 MFMA. Grid (SEQ/64, NHEADS, BATCH), 256 thr (4 waves).
// ---------------------------------------------------------------------------
__global__ __launch_bounds__(256, 2)
void attn_kernel(const _Float16* __restrict__ qh, const _Float16* __restrict__ kh,
                 const _Float16* __restrict__ vt, _Float16* __restrict__ ao) {
    __shared__ __align__(16) char smem[57344];
    char* Qs = smem;             // [64 rows][256 B] swizzled
    char* Ks = smem + 16384;     // [64 rows][256 B] swizzled
    char* Vs = smem + 32768;     // [128 rows][128 B] swizzled
    char* Ps = smem + 49152;     // 4 waves x [16 rows][128 B] swizzled

    const int tid = threadIdx.x, lane = tid & 63, w = tid >> 6;
    const int qt0 = blockIdx.x << 6;
    const int h = blockIdx.y, b = blockIdx.z;
    const int g = h >> 3;
    const _Float16* qbase = qh + ((size_t)(b * NHEADS + h) * SEQ + qt0) * HDIM;
    const _Float16* kbase = kh + (size_t)(b * NGROUPS + g) * SEQ * HDIM;
    const _Float16* vbase = vt + (size_t)(b * NGROUPS + g) * HDIM * SEQ;

#pragma unroll
    for (int it = 0; it < 4; ++it) {
        int c = it * 256 + tid;
        int row = c >> 4, jc = c & 15;
        int sj = jc ^ (row & 7);
        glds16((const char*)(qbase + (size_t)row * HDIM) + (sj << 4),
               Qs + (it * 256 + (tid & 192)) * 16);
    }

    float m_run[4] = {-1e30f, -1e30f, -1e30f, -1e30f};
    float l_run[4] = {0.f, 0.f, 0.f, 0.f};
    const f32x4 fz = {0.f, 0.f, 0.f, 0.f};
    f32x4 oacc[8];
#pragma unroll
    for (int i = 0; i < 8; ++i) oacc[i] = fz;

    const int qrow  = w * 16 + (lane & 15);
    const int qroff = qrow * 256;
    const int qswz  = qrow & 7;
    char* Pw = Ps + w * 2048;
    const int prow  = lane & 15;
    const int pswz  = prow & 7;

    for (int t0 = 0; t0 < SEQ; t0 += 64) {
        __syncthreads();
#pragma unroll
        for (int it = 0; it < 4; ++it) {           // stage K tile
            int c = it * 256 + tid;
            int row = c >> 4, jc = c & 15;
            int sj = jc ^ (row & 7);
            glds16((const char*)(kbase + (size_t)(t0 + row) * HDIM) + (sj << 4),
                   Ks + (it * 256 + (tid & 192)) * 16);
        }
#pragma unroll
        for (int it = 0; it < 4; ++it) {           // stage V^T tile
            int c = it * 256 + tid;
            int d = c >> 3, jc = c & 7;
            int sj = jc ^ (d & 7);
            glds16((const char*)(vbase + (size_t)d * SEQ + t0) + (sj << 4),
                   Vs + (it * 256 + (tid & 192)) * 16);
        }
        __syncthreads();

        // ---- S = Q K^T ----
        f32x4 sacc[4];
#pragma unroll
        for (int i = 0; i < 4; ++i) sacc[i] = fz;
#pragma unroll
        for (int ks = 0; ks < 4; ++ks) {
            int chA = ks * 4 + (lane >> 4);
            f16x8 af = *reinterpret_cast<const f16x8*>(Qs + qroff + ((chA ^ qswz) << 4));
#pragma unroll
            for (int nf = 0; nf < 4; ++nf) {
                int trow = nf * 16 + (lane & 15);
                f16x8 bf = *reinterpret_cast<const f16x8*>(
                    Ks + trow * 256 + (((ks * 4 + (lane >> 4)) ^ (trow & 7)) << 4));
                sacc[nf] = __builtin_amdgcn_mfma_f32_16x16x32_f16(af, bf, sacc[nf], 0, 0, 0);
            }
        }

        // ---- online softmax ----
        float mnew[4], scl[4], psum[4];
#pragma unroll
        for (int r = 0; r < 4; ++r) {
            float pm = fmaxf(fmaxf(sacc[0][r], sacc[1][r]), fmaxf(sacc[2][r], sacc[3][r]));
            pm = fmaxf(pm, __shfl_xor(pm, 1, 16));
            pm = fmaxf(pm, __shfl_xor(pm, 2, 16));
            pm = fmaxf(pm, __shfl_xor(pm, 4, 16));
            pm = fmaxf(pm, __shfl_xor(pm, 8, 16));
            mnew[r] = fmaxf(m_run[r], pm);
            scl[r] = __expf(m_run[r] - mnew[r]);
            m_run[r] = mnew[r];
            psum[r] = 0.f;
        }
#pragma unroll
        for (int nf = 0; nf < 4; ++nf)
#pragma unroll
            for (int r = 0; r < 4; ++r) {
                float p = __expf(sacc[nf][r] - mnew[r]);
                sacc[nf][r] = p;
                psum[r] += p;
            }
#pragma unroll
        for (int r = 0; r < 4; ++r) {
            float ps = psum[r];
            ps += __shfl_xor(ps, 1, 16);
            ps += __shfl_xor(ps, 2, 16);
            ps += __shfl_xor(ps, 4, 16);
            ps += __shfl_xor(ps, 8, 16);
            l_run[r] = l_run[r] * scl[r] + ps;
        }
#pragma unroll
        for (int i = 0; i < 8; ++i) {
            f32x4 o = oacc[i];
            o[0] *= scl[0]; o[1] *= scl[1]; o[2] *= scl[2]; o[3] *= scl[3];
            oacc[i] = o;
        }

        // ---- P -> wave-private swizzled LDS (fp16) ----
#pragma unroll
        for (int nf = 0; nf < 4; ++nf)
#pragma unroll
            for (int r = 0; r < 4; ++r) {
                int pr = ((lane >> 4) << 2) + r;
                int pc = nf * 16 + (lane & 15);
                int byte = pr * 128 + ((pc * 2) ^ ((pr & 7) << 4));
                *reinterpret_cast<_Float16*>(Pw + byte) = (_Float16)sacc[nf][r];
            }

        // ---- O += P V ----
#pragma unroll
        for (int ks = 0; ks < 2; ++ks) {
            int chP = ks * 4 + (lane >> 4);
            f16x8 pa = *reinterpret_cast<const f16x8*>(Pw + prow * 128 + ((chP ^ pswz) << 4));
#pragma unroll
            for (int nf = 0; nf < 8; ++nf) {
                int vrow = nf * 16 + (lane & 15);
                f16x8 vf = *reinterpret_cast<const f16x8*>(
                    Vs + vrow * 128 + (((ks * 4 + (lane >> 4)) ^ (vrow & 7)) << 4));
                oacc[nf] = __builtin_amdgcn_mfma_f32_16x16x32_f16(pa, vf, oacc[nf], 0, 0, 0);
            }
        }
    }

    // ---- epilogue: normalize, write fp16 ----
#pragma unroll
    for (int nf = 0; nf < 8; ++nf)
#pragma unroll
        for (int r = 0; r < 4; ++r) {
            int qr  = qt0 + w * 16 + ((lane >> 4) << 2) + r;
            int col = h * HDIM + nf * 16 + (lane & 15);
            float v = oacc[nf][r] / l_run[r];
            ao[(size_t)(b * SEQ + qr) * DMODEL + col] = (_Float16)v;
        }
}

// ---------------------------------------------------------------------------
extern "C" void kernel_launch(void* const* d_in, const int* in_sizes, int n_in,
                              void* d_out, int out_size, void* d_ws, size_t ws_size,
                              hipStream_t stream) {
    const float* x  = (const float*)d_in[0];
    const float* Wq = (const float*)d_in[1];
    const float* bq = (const float*)d_in[2];
    const float* Wk = (const float*)d_in[3];
    const float* bk = (const float*)d_in[4];
    const float* Wv = (const float*)d_in[5];
    const float* bv = (const float*)d_in[6];
    const float* Wo = (const float*)d_in[7];
    const float* bo = (const float*)d_in[8];
    float* out = (float*)d_out;

    char* ws = (char*)d_ws;
    _Float16* xs     = (_Float16*)(ws);                    // 16.78 MB [4096][2048]
    _Float16* wqkv16 = (_Float16*)(ws + 16777216);         // 10.49 MB [2560][2048]
    _Float16* wot16  = (_Float16*)(ws + 27262976);         //  8.39 MB [2048][2048]
    _Float16* qkv16  = (_Float16*)(ws + 35651584);         // 20.97 MB [4096][2560]
    _Float16* qhb    = (_Float16*)(ws + 56623104);         // 16.78 MB [B][H][S][D]
    _Float16* khb    = (_Float16*)(ws + 73400320);         //  2.10 MB [B][G][S][D]
    _Float16* vtb    = (_Float16*)(ws + 75497472);         //  2.10 MB [B][G][D][S]
    float*    sint   = (float*)(ws + 77594624);            //  0.26 MB
    float*    cost   = (float*)(ws + 77856768);            //  0.26 MB
    float*    bias_c = (float*)(ws + 78118912);            //  10 KB
    _Float16* ao = xs;   // attention output reuses xs (x dead after QKV GEMM)

    rope_table_kernel<<<SEQ * 64 / 256, 256, 0, stream>>>(sint, cost);
    convert_x_kernel<<<ROWS * DMODEL / 8 / 256, 256, 0, stream>>>(x, xs);
    transpose_w_kernel<<<dim3(32, 32), 256, 0, stream>>>(Wq, DMODEL, wqkv16, 0, DMODEL);
    transpose_w_kernel<<<dim3(4, 32),  256, 0, stream>>>(Wk, 256,    wqkv16, 2048, DMODEL);
    transpose_w_kernel<<<dim3(4, 32),  256, 0, stream>>>(Wv, 256,    wqkv16, 2304, DMODEL);
    transpose_w_kernel<<<dim3(32, 32), 256, 0, stream>>>(Wo, DMODEL, wot16,  0, DMODEL);
    bias_cat_kernel<<<10, 256, 0, stream>>>(bq, bk, bv, bias_c);

    // QKV projection: [4096][2048] @ [2048][2560] -> fp16 [4096][2560]
    gemm_fp16_kernel<1><<<(ROWS / 128) * (NQKV / 128), 256, 0, stream>>>(
        xs, wqkv16, bias_c, qkv16, ROWS, NQKV, DMODEL);

    rope_qk_kernel<<<(ROWS * (NHEADS + NGROUPS) * 8) / 256, 256, 0, stream>>>(
        qkv16, sint, cost, qhb, khb);
    transpose_v_kernel<<<dim3(SEQ / 64, HDIM / 64, BATCH * NGROUPS), 256, 0, stream>>>(qkv16, vtb);

    attn_kernel<<<dim3(SEQ / 64, NHEADS, BATCH), 256, 0, stream>>>(qhb, khb, vtb, ao);

    // Output projection: [4096][2048] @ [2048][2048] -> fp32 out
    gemm_fp16_kernel<0><<<(ROWS / 128) * (DMODEL / 128), 256, 0, stream>>>(
        ao, wot16, bo, out, ROWS, DMODEL, DMODEL);
}

// Round 6
// 318.904 us; speedup vs baseline: 6.9060x; 1.0189x over previous
//
#include <hip/hip_runtime.h>
#include <hip/hip_bf16.h>
#include <hip/hip_fp16.h>
#include <math.h>

#define BATCH   4
#define SEQ     1024
#define DMODEL  2048
#define NHEADS  16
#define NGROUPS 2
#define HDIM    128
#define ROWS    (BATCH * SEQ)      // 4096
#define NQKV    2560               // 2048 q + 256 k + 256 v

typedef float    f32x4 __attribute__((ext_vector_type(4)));
typedef _Float16 f16x8 __attribute__((ext_vector_type(8)));

__device__ __forceinline__ void glds16(const void* g, void* s) {
    __builtin_amdgcn_global_load_lds(
        (__attribute__((address_space(1))) void*)g,
        (__attribute__((address_space(3))) void*)s, 16, 0, 0);
}

// ---------------------------------------------------------------------------
// RoPE tables: sin/cos[p][j], p in [0,SEQ), j in [0,64)
// ---------------------------------------------------------------------------
__global__ void rope_table_kernel(float* __restrict__ sin_t, float* __restrict__ cos_t) {
    int idx = blockIdx.x * 256 + threadIdx.x;
    int p = idx >> 6, j = idx & 63;
    float inv = powf(10000.0f, -(float)j * (1.0f / 64.0f));
    float f = (float)p * inv;
    sin_t[idx] = sinf(f);
    cos_t[idx] = cosf(f);
}

// ---------------------------------------------------------------------------
// Convert x fp32 -> fp16, 8 elems/thread.
// ---------------------------------------------------------------------------
__global__ void convert_x_kernel(const float* __restrict__ x, _Float16* __restrict__ xo) {
    int i = (blockIdx.x * 256 + threadIdx.x) * 8;
    float v[8];
    *reinterpret_cast<float4*>(&v[0]) = *reinterpret_cast<const float4*>(x + i);
    *reinterpret_cast<float4*>(&v[4]) = *reinterpret_cast<const float4*>(x + i + 4);
    f16x8 h;
#pragma unroll
    for (int j = 0; j < 8; ++j) h[j] = (_Float16)v[j];
    *reinterpret_cast<f16x8*>(xo + i) = h;
}

// ---------------------------------------------------------------------------
// Transpose W [K][N] fp32 -> fp16 [N][K] (dst row offset drow0).
// ---------------------------------------------------------------------------
__global__ __launch_bounds__(256)
void transpose_w_kernel(const float* __restrict__ W, int ldw,
                        _Float16* __restrict__ dst, int drow0, int K) {
    __shared__ float tile[64][65];
    int n0 = blockIdx.x * 64, k0 = blockIdx.y * 64;
#pragma unroll
    for (int it = 0; it < 16; ++it) {
        int e = it * 256 + threadIdx.x;
        int r = e >> 6, c = e & 63;
        tile[r][c] = W[(size_t)(k0 + r) * ldw + n0 + c];
    }
    __syncthreads();
#pragma unroll
    for (int it = 0; it < 16; ++it) {
        int e = it * 256 + threadIdx.x;
        int nr = e >> 6, kc = e & 63;
        dst[(size_t)(drow0 + n0 + nr) * K + k0 + kc] = (_Float16)tile[kc][nr];
    }
}

// ---------------------------------------------------------------------------
__global__ void bias_cat_kernel(const float* __restrict__ bq, const float* __restrict__ bk,
                                const float* __restrict__ bv, float* __restrict__ bc) {
    int i = blockIdx.x * 256 + threadIdx.x;
    if (i >= NQKV) return;
    bc[i] = (i < 2048) ? bq[i] : ((i < 2304) ? bk[i - 2048] : bv[i - 2304]);
}

// ---------------------------------------------------------------------------
// fp16 GEMM: C[M][N] = A[M][K] @ Bt^T[N][K] + bias.  (unchanged from round 5)
// ---------------------------------------------------------------------------
template<int OUT_HALF>
__global__ __launch_bounds__(256, 3)
void gemm_fp16_kernel(const _Float16* __restrict__ A, const _Float16* __restrict__ Bt,
                      const float* __restrict__ bias, void* __restrict__ Cout,
                      int M, int N, int K) {
    __shared__ __align__(16) _Float16 lds[16384];   // 32 KB: A [128][64], B [128][64]
    _Float16* As = lds;
    _Float16* Bs = lds + 8192;

    const int tid  = threadIdx.x;
    const int lane = tid & 63;
    const int w    = tid >> 6;
    const int nbn  = N >> 7;
    const int nwg  = gridDim.x;
    const int cpx  = nwg >> 3;
    const int bid  = blockIdx.x;
    const int swz  = (bid & 7) * cpx + (bid >> 3);
    const int row0 = (swz / nbn) << 7;
    const int col0 = (swz % nbn) << 7;
    const int wr   = (w >> 1) << 6;
    const int wc   = (w & 1) << 6;

    const f32x4 fz = {0.f, 0.f, 0.f, 0.f};
    f32x4 acc[4][4];
#pragma unroll
    for (int i = 0; i < 4; ++i)
#pragma unroll
        for (int j = 0; j < 4; ++j) acc[i][j] = fz;

    for (int k0 = 0; k0 < K; k0 += 64) {
        __syncthreads();
#pragma unroll
        for (int it = 0; it < 4; ++it) {
            int chunk = it * 256 + tid;
            int trow  = chunk >> 3;
            int jp    = chunk & 7;
            int j     = jp ^ (trow & 7);
            size_t aoff = (size_t)(row0 + trow) * K + k0 + j * 8;
            size_t boff = (size_t)(col0 + trow) * K + k0 + j * 8;
            int ldst = (it * 256 + (tid & 192)) * 16;
            glds16(A  + aoff, (char*)As + ldst);
            glds16(Bt + boff, (char*)Bs + ldst);
        }
        __syncthreads();

#pragma unroll
        for (int ks = 0; ks < 2; ++ks) {
            f16x8 a4[4], b4[4];
            int ja = ks * 4 + (lane >> 4);
#pragma unroll
            for (int i = 0; i < 4; ++i) {
                int ar = wr + i * 16 + (lane & 15);
                a4[i] = *reinterpret_cast<const f16x8*>(
                    (const char*)As + ar * 128 + ((ja ^ (ar & 7)) << 4));
                int br = wc + i * 16 + (lane & 15);
                b4[i] = *reinterpret_cast<const f16x8*>(
                    (const char*)Bs + br * 128 + ((ja ^ (br & 7)) << 4));
            }
#pragma unroll
            for (int i = 0; i < 4; ++i)
#pragma unroll
                for (int j = 0; j < 4; ++j)
                    acc[i][j] = __builtin_amdgcn_mfma_f32_16x16x32_f16(a4[i], b4[j], acc[i][j], 0, 0, 0);
        }
    }

    float bv4[4];
#pragma unroll
    for (int j = 0; j < 4; ++j) bv4[j] = bias[col0 + wc + j * 16 + (lane & 15)];
#pragma unroll
    for (int i = 0; i < 4; ++i)
#pragma unroll
        for (int j = 0; j < 4; ++j)
#pragma unroll
            for (int r = 0; r < 4; ++r) {
                int grow = row0 + wr + i * 16 + ((lane >> 4) << 2) + r;
                int gcol = col0 + wc + j * 16 + (lane & 15);
                float v = acc[i][j][r] + bv4[j];
                if (OUT_HALF)
                    ((_Float16*)Cout)[(size_t)grow * N + gcol] = (_Float16)v;
                else
                    ((float*)Cout)[(size_t)grow * N + gcol] = v;
            }
}

// ---------------------------------------------------------------------------
// RoPE on k only (q handled in-register inside attn). kh: [B][G][S][D].
// ---------------------------------------------------------------------------
__global__ void rope_k_kernel(const _Float16* __restrict__ qkv,
                              const float* __restrict__ sin_t, const float* __restrict__ cos_t,
                              _Float16* __restrict__ kh) {
    int idx = blockIdx.x * 256 + threadIdx.x;   // ROWS*NGROUPS*8 threads
    int jc = idx & 7, t = idx >> 3;
    int j0 = jc * 8;
    int row = t >> 1, g = t & 1;
    int b = row >> 10, s = row & 1023;
    const _Float16* src = qkv + (size_t)row * NQKV + 2048 + g * HDIM;
    _Float16* dst = kh + ((size_t)(b * NGROUPS + g) * SEQ + s) * HDIM;
    f16x8 x1 = *reinterpret_cast<const f16x8*>(src + j0);
    f16x8 x2 = *reinterpret_cast<const f16x8*>(src + j0 + 64);
    float cc[8], ss[8];
    *reinterpret_cast<float4*>(&cc[0]) = *reinterpret_cast<const float4*>(cos_t + s * 64 + j0);
    *reinterpret_cast<float4*>(&cc[4]) = *reinterpret_cast<const float4*>(cos_t + s * 64 + j0 + 4);
    *reinterpret_cast<float4*>(&ss[0]) = *reinterpret_cast<const float4*>(sin_t + s * 64 + j0);
    *reinterpret_cast<float4*>(&ss[4]) = *reinterpret_cast<const float4*>(sin_t + s * 64 + j0 + 4);
    f16x8 o1, o2;
#pragma unroll
    for (int j = 0; j < 8; ++j) {
        float f1 = (float)x1[j], f2 = (float)x2[j];
        o1[j] = (_Float16)(f1 * cc[j] - f2 * ss[j]);
        o2[j] = (_Float16)(f2 * cc[j] + f1 * ss[j]);
    }
    *reinterpret_cast<f16x8*>(dst + j0)      = o1;
    *reinterpret_cast<f16x8*>(dst + j0 + 64) = o2;
}

// ---------------------------------------------------------------------------
// V transpose: qkv v-slice -> vt [B][G][D][S] fp16 (vectorized).
// ---------------------------------------------------------------------------
__global__ __launch_bounds__(256)
void transpose_v_kernel(const _Float16* __restrict__ qkv, _Float16* __restrict__ vt) {
    __shared__ _Float16 tile[64][72];
    int s0 = blockIdx.x * 64, d0 = blockIdx.y * 64, bg = blockIdx.z;
    int b = bg >> 1, g = bg & 1;
#pragma unroll
    for (int it = 0; it < 2; ++it) {
        int c = it * 256 + threadIdx.x;
        int r = c >> 3, cc = (c & 7) * 8;
        f16x8 v = *reinterpret_cast<const f16x8*>(
            qkv + (size_t)(b * SEQ + s0 + r) * NQKV + 2304 + g * HDIM + d0 + cc);
#pragma unroll
        for (int j = 0; j < 8; ++j) tile[r][cc + j] = v[j];
    }
    __syncthreads();
#pragma unroll
    for (int it = 0; it < 2; ++it) {
        int c = it * 256 + threadIdx.x;
        int dr = c >> 3, sc = (c & 7) * 8;
        f16x8 o;
#pragma unroll
        for (int j = 0; j < 8; ++j) o[j] = tile[sc + j][dr];
        *reinterpret_cast<f16x8*>(vt + ((size_t)bg * HDIM + d0 + dr) * SEQ + s0 + sc) = o;
    }
}

// ---------------------------------------------------------------------------
// Flash attention, fp16 MFMA. Grid (SEQ/64, NHEADS, BATCH), 256 thr (4 waves).
// Q in registers with fused RoPE+scale; K/V double-buffered LDS (2-phase
// pipeline, counted vmcnt + raw s_barrier); defer-max rescale.
// ---------------------------------------------------------------------------
__global__ __launch_bounds__(256, 2)
void attn_kernel(const _Float16* __restrict__ qkv, const _Float16* __restrict__ kh,
                 const _Float16* __restrict__ vt,
                 const float* __restrict__ sin_t, const float* __restrict__ cos_t,
                 _Float16* __restrict__ ao) {
    __shared__ __align__(16) char smem[73728];
    // [0,16K) K0 | [16K,32K) V0 | [32K,48K) K1 | [48K,64K) V1 | [64K,72K) P

    const int tid = threadIdx.x, lane = tid & 63, w = tid >> 6;
    const int qt0 = blockIdx.x << 6;
    const int h = blockIdx.y, b = blockIdx.z;
    const int g = h >> 3;
    const _Float16* kbase = kh + (size_t)(b * NGROUPS + g) * SEQ * HDIM;
    const _Float16* vbase = vt + (size_t)(b * NGROUPS + g) * HDIM * SEQ;

    // ---- stage K/V tile 0 into buffer 0 (issued first, flies under prologue)
    {
        char* Kb = smem;
        char* Vb = smem + 16384;
#pragma unroll
        for (int it = 0; it < 4; ++it) {
            int c = it * 256 + tid;
            int row = c >> 4, jc = c & 15;
            int sj = jc ^ (row & 7);
            glds16((const char*)(kbase + (size_t)row * HDIM) + (sj << 4),
                   Kb + (it * 256 + (tid & 192)) * 16);
        }
#pragma unroll
        for (int it = 0; it < 4; ++it) {
            int c = it * 256 + tid;
            int d = c >> 3, jc = c & 7;
            int sj = jc ^ (d & 7);
            glds16((const char*)(vbase + (size_t)d * SEQ) + (sj << 4),
                   Vb + (it * 256 + (tid & 192)) * 16);
        }
    }

    // ---- Q fragments in registers + in-register RoPE + 1/sqrt(D) scale ----
    const int srow = qt0 + w * 16 + (lane & 15);            // position in seq
    const int sl   = lane >> 4;                             // slot sub-index
    const _Float16* qrp = qkv + (size_t)(b * SEQ + srow) * NQKV + h * HDIM;
    f16x8 af[4];
#pragma unroll
    for (int ks = 0; ks < 4; ++ks)
        af[ks] = *reinterpret_cast<const f16x8*>(qrp + (ks * 4 + sl) * 8);
    {
        const float qsc = 0.08838834764831845f;             // 1/sqrt(128)
#pragma unroll
        for (int ks = 0; ks < 2; ++ks) {
            int d0 = (ks * 4 + sl) * 8;                     // 0..56
            float cc[8], ss[8];
            *reinterpret_cast<float4*>(&cc[0]) = *reinterpret_cast<const float4*>(cos_t + srow * 64 + d0);
            *reinterpret_cast<float4*>(&cc[4]) = *reinterpret_cast<const float4*>(cos_t + srow * 64 + d0 + 4);
            *reinterpret_cast<float4*>(&ss[0]) = *reinterpret_cast<const float4*>(sin_t + srow * 64 + d0);
            *reinterpret_cast<float4*>(&ss[4]) = *reinterpret_cast<const float4*>(sin_t + srow * 64 + d0 + 4);
#pragma unroll
            for (int j = 0; j < 8; ++j) {
                float f1 = (float)af[ks][j], f2 = (float)af[ks + 2][j];
                af[ks][j]     = (_Float16)((f1 * cc[j] - f2 * ss[j]) * qsc);
                af[ks + 2][j] = (_Float16)((f2 * cc[j] + f1 * ss[j]) * qsc);
            }
        }
    }

    float m_run[4] = {-1e30f, -1e30f, -1e30f, -1e30f};
    float l_run[4] = {0.f, 0.f, 0.f, 0.f};
    const f32x4 fz = {0.f, 0.f, 0.f, 0.f};
    f32x4 oacc[8];
#pragma unroll
    for (int i = 0; i < 8; ++i) oacc[i] = fz;

    char* Pw = smem + 65536 + w * 2048;
    const int prow = lane & 15;
    const int pswz = prow & 7;

    int cur = 0;
    for (int t = 0; t < SEQ / 64; ++t) {
        char* Kb = smem + (cur << 15);
        char* Vb = Kb + 16384;
        if (t < SEQ / 64 - 1) {
            // issue next tile's staging into the other buffer (8 glds/thread)
            char* Kn = smem + ((cur ^ 1) << 15);
            char* Vn = Kn + 16384;
            int t0n = (t + 1) << 6;
#pragma unroll
            for (int it = 0; it < 4; ++it) {
                int c = it * 256 + tid;
                int row = c >> 4, jc = c & 15;
                int sj = jc ^ (row & 7);
                glds16((const char*)(kbase + (size_t)(t0n + row) * HDIM) + (sj << 4),
                       Kn + (it * 256 + (tid & 192)) * 16);
            }
#pragma unroll
            for (int it = 0; it < 4; ++it) {
                int c = it * 256 + tid;
                int d = c >> 3, jc = c & 7;
                int sj = jc ^ (d & 7);
                glds16((const char*)(vbase + (size_t)d * SEQ + t0n) + (sj << 4),
                       Vn + (it * 256 + (tid & 192)) * 16);
            }
            asm volatile("s_waitcnt vmcnt(8)" ::: "memory");
        } else {
            asm volatile("s_waitcnt vmcnt(0)" ::: "memory");
        }
        asm volatile("s_barrier" ::: "memory");   // cur tile fully staged

        // ---- S = Q K^T ----
        f32x4 sacc[4];
#pragma unroll
        for (int i = 0; i < 4; ++i) sacc[i] = fz;
#pragma unroll
        for (int ks = 0; ks < 4; ++ks) {
#pragma unroll
            for (int nf = 0; nf < 4; ++nf) {
                int trow = nf * 16 + (lane & 15);
                f16x8 bf = *reinterpret_cast<const f16x8*>(
                    Kb + trow * 256 + (((ks * 4 + (lane >> 4)) ^ (trow & 7)) << 4));
                sacc[nf] = __builtin_amdgcn_mfma_f32_16x16x32_f16(af[ks], bf, sacc[nf], 0, 0, 0);
            }
        }

        // ---- online softmax with defer-max ----
        float pm[4];
#pragma unroll
        for (int r = 0; r < 4; ++r) {
            float v = fmaxf(fmaxf(sacc[0][r], sacc[1][r]), fmaxf(sacc[2][r], sacc[3][r]));
            v = fmaxf(v, __shfl_xor(v, 1, 16));
            v = fmaxf(v, __shfl_xor(v, 2, 16));
            v = fmaxf(v, __shfl_xor(v, 4, 16));
            v = fmaxf(v, __shfl_xor(v, 8, 16));
            pm[r] = v;
        }
        float growth = fmaxf(fmaxf(pm[0] - m_run[0], pm[1] - m_run[1]),
                             fmaxf(pm[2] - m_run[2], pm[3] - m_run[3]));
        if (__any(growth > 8.0f)) {
            float scl[4];
#pragma unroll
            for (int r = 0; r < 4; ++r) {
                float mn = fmaxf(m_run[r], pm[r]);
                scl[r] = __expf(m_run[r] - mn);
                m_run[r] = mn;
                l_run[r] *= scl[r];
            }
#pragma unroll
            for (int i = 0; i < 8; ++i) {
                f32x4 o = oacc[i];
                o[0] *= scl[0]; o[1] *= scl[1]; o[2] *= scl[2]; o[3] *= scl[3];
                oacc[i] = o;
            }
        }
        float psum[4] = {0.f, 0.f, 0.f, 0.f};
#pragma unroll
        for (int nf = 0; nf < 4; ++nf)
#pragma unroll
            for (int r = 0; r < 4; ++r) {
                float p = __expf(sacc[nf][r] - m_run[r]);
                sacc[nf][r] = p;
                psum[r] += p;
            }
#pragma unroll
        for (int r = 0; r < 4; ++r) {
            float ps = psum[r];
            ps += __shfl_xor(ps, 1, 16);
            ps += __shfl_xor(ps, 2, 16);
            ps += __shfl_xor(ps, 4, 16);
            ps += __shfl_xor(ps, 8, 16);
            l_run[r] += ps;
        }

        // ---- P -> wave-private swizzled LDS (fp16) ----
#pragma unroll
        for (int nf = 0; nf < 4; ++nf)
#pragma unroll
            for (int r = 0; r < 4; ++r) {
                int pr = ((lane >> 4) << 2) + r;
                int pc = nf * 16 + (lane & 15);
                int byte = pr * 128 + ((pc * 2) ^ ((pr & 7) << 4));
                *reinterpret_cast<_Float16*>(Pw + byte) = (_Float16)sacc[nf][r];
            }

        // ---- O += P V ----
#pragma unroll
        for (int ks = 0; ks < 2; ++ks) {
            int chP = ks * 4 + (lane >> 4);
            f16x8 pa = *reinterpret_cast<const f16x8*>(Pw + prow * 128 + ((chP ^ pswz) << 4));
#pragma unroll
            for (int nf = 0; nf < 8; ++nf) {
                int vrow = nf * 16 + (lane & 15);
                f16x8 vf = *reinterpret_cast<const f16x8*>(
                    Vb + vrow * 128 + (((ks * 4 + (lane >> 4)) ^ (vrow & 7)) << 4));
                oacc[nf] = __builtin_amdgcn_mfma_f32_16x16x32_f16(pa, vf, oacc[nf], 0, 0, 0);
            }
        }

        asm volatile("s_barrier" ::: "memory");   // all waves done reading cur
        cur ^= 1;
    }

    // ---- epilogue: normalize, write fp16 ----
#pragma unroll
    for (int nf = 0; nf < 8; ++nf)
#pragma unroll
        for (int r = 0; r < 4; ++r) {
            int qr  = qt0 + w * 16 + ((lane >> 4) << 2) + r;
            int col = h * HDIM + nf * 16 + (lane & 15);
            float v = oacc[nf][r] / l_run[r];
            ao[(size_t)(b * SEQ + qr) * DMODEL + col] = (_Float16)v;
        }
}

// ---------------------------------------------------------------------------
extern "C" void kernel_launch(void* const* d_in, const int* in_sizes, int n_in,
                              void* d_out, int out_size, void* d_ws, size_t ws_size,
                              hipStream_t stream) {
    const float* x  = (const float*)d_in[0];
    const float* Wq = (const float*)d_in[1];
    const float* bq = (const float*)d_in[2];
    const float* Wk = (const float*)d_in[3];
    const float* bk = (const float*)d_in[4];
    const float* Wv = (const float*)d_in[5];
    const float* bv = (const float*)d_in[6];
    const float* Wo = (const float*)d_in[7];
    const float* bo = (const float*)d_in[8];
    float* out = (float*)d_out;

    char* ws = (char*)d_ws;
    _Float16* xs     = (_Float16*)(ws);                    // 16.78 MB [4096][2048]
    _Float16* wqkv16 = (_Float16*)(ws + 16777216);         // 10.49 MB [2560][2048]
    _Float16* wot16  = (_Float16*)(ws + 27262976);         //  8.39 MB [2048][2048]
    _Float16* qkv16  = (_Float16*)(ws + 35651584);         // 20.97 MB [4096][2560]
    _Float16* khb    = (_Float16*)(ws + 56623104);         //  2.10 MB [B][G][S][D]
    _Float16* vtb    = (_Float16*)(ws + 58720256);         //  2.10 MB [B][G][D][S]
    float*    sint   = (float*)(ws + 60817408);            //  0.26 MB
    float*    cost   = (float*)(ws + 61079552);            //  0.26 MB
    float*    bias_c = (float*)(ws + 61341696);            //  10 KB
    _Float16* ao = xs;   // attention output reuses xs (x dead after QKV GEMM)

    rope_table_kernel<<<SEQ * 64 / 256, 256, 0, stream>>>(sint, cost);
    convert_x_kernel<<<ROWS * DMODEL / 8 / 256, 256, 0, stream>>>(x, xs);
    transpose_w_kernel<<<dim3(32, 32), 256, 0, stream>>>(Wq, DMODEL, wqkv16, 0, DMODEL);
    transpose_w_kernel<<<dim3(4, 32),  256, 0, stream>>>(Wk, 256,    wqkv16, 2048, DMODEL);
    transpose_w_kernel<<<dim3(4, 32),  256, 0, stream>>>(Wv, 256,    wqkv16, 2304, DMODEL);
    transpose_w_kernel<<<dim3(32, 32), 256, 0, stream>>>(Wo, DMODEL, wot16,  0, DMODEL);
    bias_cat_kernel<<<10, 256, 0, stream>>>(bq, bk, bv, bias_c);

    // QKV projection: [4096][2048] @ [2048][2560] -> fp16 [4096][2560]
    gemm_fp16_kernel<1><<<(ROWS / 128) * (NQKV / 128), 256, 0, stream>>>(
        xs, wqkv16, bias_c, qkv16, ROWS, NQKV, DMODEL);

    rope_k_kernel<<<(ROWS * NGROUPS * 8) / 256, 256, 0, stream>>>(qkv16, sint, cost, khb);
    transpose_v_kernel<<<dim3(SEQ / 64, HDIM / 64, BATCH * NGROUPS), 256, 0, stream>>>(qkv16, vtb);

    attn_kernel<<<dim3(SEQ / 64, NHEADS, BATCH), 256, 0, stream>>>(
        qkv16, khb, vtb, sint, cost, ao);

    // Output projection: [4096][2048] @ [2048][2048] -> fp32 out
    gemm_fp16_kernel<0><<<(ROWS / 128) * (DMODEL / 128), 256, 0, stream>>>(
        ao, wot16, bo, out, ROWS, DMODEL, DMODEL);
}

// Round 7
// 293.394 us; speedup vs baseline: 7.5065x; 1.0869x over previous
//
#include <hip/hip_runtime.h>
#include <hip/hip_bf16.h>
#include <hip/hip_fp16.h>
#include <math.h>

#define BATCH   4
#define SEQ     1024
#define DMODEL  2048
#define NHEADS  16
#define NGROUPS 2
#define HDIM    128
#define ROWS    (BATCH * SEQ)      // 4096
#define NQKV    2560               // 2048 q + 256 k + 256 v

typedef float    f32x4 __attribute__((ext_vector_type(4)));
typedef _Float16 f16x8 __attribute__((ext_vector_type(8)));

__device__ __forceinline__ void glds16(const void* g, void* s) {
    __builtin_amdgcn_global_load_lds(
        (__attribute__((address_space(1))) void*)g,
        (__attribute__((address_space(3))) void*)s, 16, 0, 0);
}

// 16-lane (row) reductions via DPP — pure VALU, no LDS-pipe ds_swizzle.
__device__ __forceinline__ float red16_max(float v) {
    v = fmaxf(v, __int_as_float(__builtin_amdgcn_mov_dpp(__float_as_int(v), 0xB1, 0xF, 0xF, true)));  // quad xor1
    v = fmaxf(v, __int_as_float(__builtin_amdgcn_mov_dpp(__float_as_int(v), 0x4E, 0xF, 0xF, true)));  // quad xor2
    v = fmaxf(v, __int_as_float(__builtin_amdgcn_mov_dpp(__float_as_int(v), 0x124, 0xF, 0xF, true))); // row_ror:4
    v = fmaxf(v, __int_as_float(__builtin_amdgcn_mov_dpp(__float_as_int(v), 0x128, 0xF, 0xF, true))); // row_ror:8
    return v;
}
__device__ __forceinline__ float red16_sum(float v) {
    v += __int_as_float(__builtin_amdgcn_mov_dpp(__float_as_int(v), 0xB1, 0xF, 0xF, true));
    v += __int_as_float(__builtin_amdgcn_mov_dpp(__float_as_int(v), 0x4E, 0xF, 0xF, true));
    v += __int_as_float(__builtin_amdgcn_mov_dpp(__float_as_int(v), 0x124, 0xF, 0xF, true));
    v += __int_as_float(__builtin_amdgcn_mov_dpp(__float_as_int(v), 0x128, 0xF, 0xF, true));
    return v;
}

// ---------------------------------------------------------------------------
// RoPE tables: sin/cos[p][j], p in [0,SEQ), j in [0,64)
// ---------------------------------------------------------------------------
__global__ void rope_table_kernel(float* __restrict__ sin_t, float* __restrict__ cos_t) {
    int idx = blockIdx.x * 256 + threadIdx.x;
    int p = idx >> 6, j = idx & 63;
    float inv = powf(10000.0f, -(float)j * (1.0f / 64.0f));
    float f = (float)p * inv;
    sin_t[idx] = sinf(f);
    cos_t[idx] = cosf(f);
}

// ---------------------------------------------------------------------------
// Convert x fp32 -> fp16, 8 elems/thread.
// ---------------------------------------------------------------------------
__global__ void convert_x_kernel(const float* __restrict__ x, _Float16* __restrict__ xo) {
    int i = (blockIdx.x * 256 + threadIdx.x) * 8;
    float v[8];
    *reinterpret_cast<float4*>(&v[0]) = *reinterpret_cast<const float4*>(x + i);
    *reinterpret_cast<float4*>(&v[4]) = *reinterpret_cast<const float4*>(x + i + 4);
    f16x8 h;
#pragma unroll
    for (int j = 0; j < 8; ++j) h[j] = (_Float16)v[j];
    *reinterpret_cast<f16x8*>(xo + i) = h;
}

// ---------------------------------------------------------------------------
// Transpose W [K][N] fp32 -> fp16 [N][K] (dst row offset drow0).
// ---------------------------------------------------------------------------
__global__ __launch_bounds__(256)
void transpose_w_kernel(const float* __restrict__ W, int ldw,
                        _Float16* __restrict__ dst, int drow0, int K) {
    __shared__ float tile[64][65];
    int n0 = blockIdx.x * 64, k0 = blockIdx.y * 64;
#pragma unroll
    for (int it = 0; it < 16; ++it) {
        int e = it * 256 + threadIdx.x;
        int r = e >> 6, c = e & 63;
        tile[r][c] = W[(size_t)(k0 + r) * ldw + n0 + c];
    }
    __syncthreads();
#pragma unroll
    for (int it = 0; it < 16; ++it) {
        int e = it * 256 + threadIdx.x;
        int nr = e >> 6, kc = e & 63;
        dst[(size_t)(drow0 + n0 + nr) * K + k0 + kc] = (_Float16)tile[kc][nr];
    }
}

// ---------------------------------------------------------------------------
__global__ void bias_cat_kernel(const float* __restrict__ bq, const float* __restrict__ bk,
                                const float* __restrict__ bv, float* __restrict__ bc) {
    int i = blockIdx.x * 256 + threadIdx.x;
    if (i >= NQKV) return;
    bc[i] = (i < 2048) ? bq[i] : ((i < 2304) ? bk[i - 2048] : bv[i - 2304]);
}

// ---------------------------------------------------------------------------
// fp16 GEMM: C[M][N] = A[M][K] @ Bt^T[N][K] + bias.  (unchanged)
// ---------------------------------------------------------------------------
template<int OUT_HALF>
__global__ __launch_bounds__(256, 3)
void gemm_fp16_kernel(const _Float16* __restrict__ A, const _Float16* __restrict__ Bt,
                      const float* __restrict__ bias, void* __restrict__ Cout,
                      int M, int N, int K) {
    __shared__ __align__(16) _Float16 lds[16384];   // 32 KB: A [128][64], B [128][64]
    _Float16* As = lds;
    _Float16* Bs = lds + 8192;

    const int tid  = threadIdx.x;
    const int lane = tid & 63;
    const int w    = tid >> 6;
    const int nbn  = N >> 7;
    const int nwg  = gridDim.x;
    const int cpx  = nwg >> 3;
    const int bid  = blockIdx.x;
    const int swz  = (bid & 7) * cpx + (bid >> 3);
    const int row0 = (swz / nbn) << 7;
    const int col0 = (swz % nbn) << 7;
    const int wr   = (w >> 1) << 6;
    const int wc   = (w & 1) << 6;

    const f32x4 fz = {0.f, 0.f, 0.f, 0.f};
    f32x4 acc[4][4];
#pragma unroll
    for (int i = 0; i < 4; ++i)
#pragma unroll
        for (int j = 0; j < 4; ++j) acc[i][j] = fz;

    for (int k0 = 0; k0 < K; k0 += 64) {
        __syncthreads();
#pragma unroll
        for (int it = 0; it < 4; ++it) {
            int chunk = it * 256 + tid;
            int trow  = chunk >> 3;
            int jp    = chunk & 7;
            int j     = jp ^ (trow & 7);
            size_t aoff = (size_t)(row0 + trow) * K + k0 + j * 8;
            size_t boff = (size_t)(col0 + trow) * K + k0 + j * 8;
            int ldst = (it * 256 + (tid & 192)) * 16;
            glds16(A  + aoff, (char*)As + ldst);
            glds16(Bt + boff, (char*)Bs + ldst);
        }
        __syncthreads();

#pragma unroll
        for (int ks = 0; ks < 2; ++ks) {
            f16x8 a4[4], b4[4];
            int ja = ks * 4 + (lane >> 4);
#pragma unroll
            for (int i = 0; i < 4; ++i) {
                int ar = wr + i * 16 + (lane & 15);
                a4[i] = *reinterpret_cast<const f16x8*>(
                    (const char*)As + ar * 128 + ((ja ^ (ar & 7)) << 4));
                int br = wc + i * 16 + (lane & 15);
                b4[i] = *reinterpret_cast<const f16x8*>(
                    (const char*)Bs + br * 128 + ((ja ^ (br & 7)) << 4));
            }
#pragma unroll
            for (int i = 0; i < 4; ++i)
#pragma unroll
                for (int j = 0; j < 4; ++j)
                    acc[i][j] = __builtin_amdgcn_mfma_f32_16x16x32_f16(a4[i], b4[j], acc[i][j], 0, 0, 0);
        }
    }

    float bv4[4];
#pragma unroll
    for (int j = 0; j < 4; ++j) bv4[j] = bias[col0 + wc + j * 16 + (lane & 15)];
#pragma unroll
    for (int i = 0; i < 4; ++i)
#pragma unroll
        for (int j = 0; j < 4; ++j)
#pragma unroll
            for (int r = 0; r < 4; ++r) {
                int grow = row0 + wr + i * 16 + ((lane >> 4) << 2) + r;
                int gcol = col0 + wc + j * 16 + (lane & 15);
                float v = acc[i][j][r] + bv4[j];
                if (OUT_HALF)
                    ((_Float16*)Cout)[(size_t)grow * N + gcol] = (_Float16)v;
                else
                    ((float*)Cout)[(size_t)grow * N + gcol] = v;
            }
}

// ---------------------------------------------------------------------------
// RoPE on k only. kh: [B][G][S][D].
// ---------------------------------------------------------------------------
__global__ void rope_k_kernel(const _Float16* __restrict__ qkv,
                              const float* __restrict__ sin_t, const float* __restrict__ cos_t,
                              _Float16* __restrict__ kh) {
    int idx = blockIdx.x * 256 + threadIdx.x;
    int jc = idx & 7, t = idx >> 3;
    int j0 = jc * 8;
    int row = t >> 1, g = t & 1;
    int b = row >> 10, s = row & 1023;
    const _Float16* src = qkv + (size_t)row * NQKV + 2048 + g * HDIM;
    _Float16* dst = kh + ((size_t)(b * NGROUPS + g) * SEQ + s) * HDIM;
    f16x8 x1 = *reinterpret_cast<const f16x8*>(src + j0);
    f16x8 x2 = *reinterpret_cast<const f16x8*>(src + j0 + 64);
    float cc[8], ss[8];
    *reinterpret_cast<float4*>(&cc[0]) = *reinterpret_cast<const float4*>(cos_t + s * 64 + j0);
    *reinterpret_cast<float4*>(&cc[4]) = *reinterpret_cast<const float4*>(cos_t + s * 64 + j0 + 4);
    *reinterpret_cast<float4*>(&ss[0]) = *reinterpret_cast<const float4*>(sin_t + s * 64 + j0);
    *reinterpret_cast<float4*>(&ss[4]) = *reinterpret_cast<const float4*>(sin_t + s * 64 + j0 + 4);
    f16x8 o1, o2;
#pragma unroll
    for (int j = 0; j < 8; ++j) {
        float f1 = (float)x1[j], f2 = (float)x2[j];
        o1[j] = (_Float16)(f1 * cc[j] - f2 * ss[j]);
        o2[j] = (_Float16)(f2 * cc[j] + f1 * ss[j]);
    }
    *reinterpret_cast<f16x8*>(dst + j0)      = o1;
    *reinterpret_cast<f16x8*>(dst + j0 + 64) = o2;
}

// ---------------------------------------------------------------------------
// V transpose: qkv v-slice -> vt [B][G][D][S] fp16 (vectorized).
// ---------------------------------------------------------------------------
__global__ __launch_bounds__(256)
void transpose_v_kernel(const _Float16* __restrict__ qkv, _Float16* __restrict__ vt) {
    __shared__ _Float16 tile[64][72];
    int s0 = blockIdx.x * 64, d0 = blockIdx.y * 64, bg = blockIdx.z;
    int b = bg >> 1, g = bg & 1;
#pragma unroll
    for (int it = 0; it < 2; ++it) {
        int c = it * 256 + threadIdx.x;
        int r = c >> 3, cc = (c & 7) * 8;
        f16x8 v = *reinterpret_cast<const f16x8*>(
            qkv + (size_t)(b * SEQ + s0 + r) * NQKV + 2304 + g * HDIM + d0 + cc);
#pragma unroll
        for (int j = 0; j < 8; ++j) tile[r][cc + j] = v[j];
    }
    __syncthreads();
#pragma unroll
    for (int it = 0; it < 2; ++it) {
        int c = it * 256 + threadIdx.x;
        int dr = c >> 3, sc = (c & 7) * 8;
        f16x8 o;
#pragma unroll
        for (int j = 0; j < 8; ++j) o[j] = tile[sc + j][dr];
        *reinterpret_cast<f16x8*>(vt + ((size_t)bg * HDIM + d0 + dr) * SEQ + s0 + sc) = o;
    }
}

// ---------------------------------------------------------------------------
// Flash attention, fp16 MFMA. Grid (SEQ/128, NHEADS, BATCH), 256 thr (4 waves).
// Each wave owns 32 q-rows (two 16-row halves m=0,1): K/V fragments are
// reused across both halves -> LDS bytes per MFMA halved. Softmax row
// reductions via DPP (no LDS traffic). K/V double-buffered, counted vmcnt.
// ---------------------------------------------------------------------------
__global__ __launch_bounds__(256, 2)
void attn_kernel(const _Float16* __restrict__ qkv, const _Float16* __restrict__ kh,
                 const _Float16* __restrict__ vt,
                 const float* __restrict__ sin_t, const float* __restrict__ cos_t,
                 _Float16* __restrict__ ao) {
    __shared__ __align__(16) char smem[81920];
    // [0,16K) K0 | [16K,32K) V0 | [32K,48K) K1 | [48K,64K) V1 | [64K,80K) P

    const int tid = threadIdx.x, lane = tid & 63, w = tid >> 6;
    const int qt0 = blockIdx.x << 7;            // 128 q rows per block
    const int h = blockIdx.y, b = blockIdx.z;
    const int g = h >> 3;
    const _Float16* kbase = kh + (size_t)(b * NGROUPS + g) * SEQ * HDIM;
    const _Float16* vbase = vt + (size_t)(b * NGROUPS + g) * HDIM * SEQ;

    // ---- stage K/V tile 0 into buffer 0 ----
    {
        char* Kb = smem;
        char* Vb = smem + 16384;
#pragma unroll
        for (int it = 0; it < 4; ++it) {
            int c = it * 256 + tid;
            int row = c >> 4, jc = c & 15;
            int sj = jc ^ (row & 7);
            glds16((const char*)(kbase + (size_t)row * HDIM) + (sj << 4),
                   Kb + (it * 256 + (tid & 192)) * 16);
        }
#pragma unroll
        for (int it = 0; it < 4; ++it) {
            int c = it * 256 + tid;
            int d = c >> 3, jc = c & 7;
            int sj = jc ^ (d & 7);
            glds16((const char*)(vbase + (size_t)d * SEQ) + (sj << 4),
                   Vb + (it * 256 + (tid & 192)) * 16);
        }
    }

    // ---- Q fragments (two 16-row halves) + in-register RoPE + scale ----
    const int sl = lane >> 4;
    f16x8 af[2][4];
#pragma unroll
    for (int m = 0; m < 2; ++m) {
        int srow = qt0 + w * 32 + m * 16 + (lane & 15);
        const _Float16* qrp = qkv + (size_t)(b * SEQ + srow) * NQKV + h * HDIM;
#pragma unroll
        for (int ks = 0; ks < 4; ++ks)
            af[m][ks] = *reinterpret_cast<const f16x8*>(qrp + (ks * 4 + sl) * 8);
        const float qsc = 0.08838834764831845f;
#pragma unroll
        for (int ks = 0; ks < 2; ++ks) {
            int d0 = (ks * 4 + sl) * 8;
            float cc[8], ss[8];
            *reinterpret_cast<float4*>(&cc[0]) = *reinterpret_cast<const float4*>(cos_t + srow * 64 + d0);
            *reinterpret_cast<float4*>(&cc[4]) = *reinterpret_cast<const float4*>(cos_t + srow * 64 + d0 + 4);
            *reinterpret_cast<float4*>(&ss[0]) = *reinterpret_cast<const float4*>(sin_t + srow * 64 + d0);
            *reinterpret_cast<float4*>(&ss[4]) = *reinterpret_cast<const float4*>(sin_t + srow * 64 + d0 + 4);
#pragma unroll
            for (int j = 0; j < 8; ++j) {
                float f1 = (float)af[m][ks][j], f2 = (float)af[m][ks + 2][j];
                af[m][ks][j]     = (_Float16)((f1 * cc[j] - f2 * ss[j]) * qsc);
                af[m][ks + 2][j] = (_Float16)((f2 * cc[j] + f1 * ss[j]) * qsc);
            }
        }
    }

    float m_run[2][4], l_run[2][4];
#pragma unroll
    for (int m = 0; m < 2; ++m)
#pragma unroll
        for (int r = 0; r < 4; ++r) { m_run[m][r] = -1e30f; l_run[m][r] = 0.f; }
    const f32x4 fz = {0.f, 0.f, 0.f, 0.f};
    f32x4 oacc[2][8];
#pragma unroll
    for (int m = 0; m < 2; ++m)
#pragma unroll
        for (int i = 0; i < 8; ++i) oacc[m][i] = fz;

    char* Pw = smem + 65536 + w * 4096;     // [32 rows][128 B] per wave
    const int prow = lane & 15;

    int cur = 0;
    for (int t = 0; t < SEQ / 64; ++t) {
        char* Kb = smem + (cur << 15);
        char* Vb = Kb + 16384;
        if (t < SEQ / 64 - 1) {
            char* Kn = smem + ((cur ^ 1) << 15);
            char* Vn = Kn + 16384;
            int t0n = (t + 1) << 6;
#pragma unroll
            for (int it = 0; it < 4; ++it) {
                int c = it * 256 + tid;
                int row = c >> 4, jc = c & 15;
                int sj = jc ^ (row & 7);
                glds16((const char*)(kbase + (size_t)(t0n + row) * HDIM) + (sj << 4),
                       Kn + (it * 256 + (tid & 192)) * 16);
            }
#pragma unroll
            for (int it = 0; it < 4; ++it) {
                int c = it * 256 + tid;
                int d = c >> 3, jc = c & 7;
                int sj = jc ^ (d & 7);
                glds16((const char*)(vbase + (size_t)d * SEQ + t0n) + (sj << 4),
                       Vn + (it * 256 + (tid & 192)) * 16);
            }
            asm volatile("s_waitcnt vmcnt(8)" ::: "memory");
        } else {
            asm volatile("s_waitcnt vmcnt(0)" ::: "memory");
        }
        asm volatile("s_barrier" ::: "memory");

        // ---- S = Q K^T (K fragment reused for both q-halves) ----
        f32x4 sacc[2][4];
#pragma unroll
        for (int m = 0; m < 2; ++m)
#pragma unroll
            for (int i = 0; i < 4; ++i) sacc[m][i] = fz;
#pragma unroll
        for (int ks = 0; ks < 4; ++ks) {
#pragma unroll
            for (int nf = 0; nf < 4; ++nf) {
                int trow = nf * 16 + (lane & 15);
                f16x8 bf = *reinterpret_cast<const f16x8*>(
                    Kb + trow * 256 + (((ks * 4 + (lane >> 4)) ^ (trow & 7)) << 4));
                sacc[0][nf] = __builtin_amdgcn_mfma_f32_16x16x32_f16(af[0][ks], bf, sacc[0][nf], 0, 0, 0);
                sacc[1][nf] = __builtin_amdgcn_mfma_f32_16x16x32_f16(af[1][ks], bf, sacc[1][nf], 0, 0, 0);
            }
        }

        // ---- online softmax (DPP row reduce) with defer-max ----
        float pm[2][4];
        float growth = -1e30f;
#pragma unroll
        for (int m = 0; m < 2; ++m)
#pragma unroll
            for (int r = 0; r < 4; ++r) {
                float v = fmaxf(fmaxf(sacc[m][0][r], sacc[m][1][r]),
                                fmaxf(sacc[m][2][r], sacc[m][3][r]));
                v = red16_max(v);
                pm[m][r] = v;
                growth = fmaxf(growth, v - m_run[m][r]);
            }
        if (__any(growth > 8.0f)) {
            float scl[2][4];
#pragma unroll
            for (int m = 0; m < 2; ++m)
#pragma unroll
                for (int r = 0; r < 4; ++r) {
                    float mn = fmaxf(m_run[m][r], pm[m][r]);
                    scl[m][r] = __expf(m_run[m][r] - mn);
                    m_run[m][r] = mn;
                    l_run[m][r] *= scl[m][r];
                }
#pragma unroll
            for (int m = 0; m < 2; ++m)
#pragma unroll
                for (int i = 0; i < 8; ++i) {
                    f32x4 o = oacc[m][i];
                    o[0] *= scl[m][0]; o[1] *= scl[m][1];
                    o[2] *= scl[m][2]; o[3] *= scl[m][3];
                    oacc[m][i] = o;
                }
        }
#pragma unroll
        for (int m = 0; m < 2; ++m)
#pragma unroll
            for (int r = 0; r < 4; ++r) {
                float ps = 0.f;
#pragma unroll
                for (int nf = 0; nf < 4; ++nf) {
                    float p = __expf(sacc[m][nf][r] - m_run[m][r]);
                    sacc[m][nf][r] = p;
                    ps += p;
                }
                l_run[m][r] += red16_sum(ps);
            }

        // ---- P -> wave-private swizzled LDS (fp16) ----
#pragma unroll
        for (int m = 0; m < 2; ++m)
#pragma unroll
            for (int nf = 0; nf < 4; ++nf)
#pragma unroll
                for (int r = 0; r < 4; ++r) {
                    int pr = m * 16 + ((lane >> 4) << 2) + r;
                    int pc = nf * 16 + (lane & 15);
                    int byte = pr * 128 + ((pc * 2) ^ ((pr & 7) << 4));
                    *reinterpret_cast<_Float16*>(Pw + byte) = (_Float16)sacc[m][nf][r];
                }

        // ---- O += P V (V fragment reused for both q-halves) ----
#pragma unroll
        for (int ks = 0; ks < 2; ++ks) {
            int chP = ks * 4 + (lane >> 4);
            f16x8 pa[2];
#pragma unroll
            for (int m = 0; m < 2; ++m)
                pa[m] = *reinterpret_cast<const f16x8*>(
                    Pw + (m * 16 + prow) * 128 + ((chP ^ (prow & 7)) << 4));
#pragma unroll
            for (int nf = 0; nf < 8; ++nf) {
                int vrow = nf * 16 + (lane & 15);
                f16x8 vf = *reinterpret_cast<const f16x8*>(
                    Vb + vrow * 128 + (((ks * 4 + (lane >> 4)) ^ (vrow & 7)) << 4));
                oacc[0][nf] = __builtin_amdgcn_mfma_f32_16x16x32_f16(pa[0], vf, oacc[0][nf], 0, 0, 0);
                oacc[1][nf] = __builtin_amdgcn_mfma_f32_16x16x32_f16(pa[1], vf, oacc[1][nf], 0, 0, 0);
            }
        }

        asm volatile("s_barrier" ::: "memory");
        cur ^= 1;
    }

    // ---- epilogue: normalize, write fp16 ----
#pragma unroll
    for (int m = 0; m < 2; ++m)
#pragma unroll
        for (int nf = 0; nf < 8; ++nf)
#pragma unroll
            for (int r = 0; r < 4; ++r) {
                int qr  = qt0 + w * 32 + m * 16 + ((lane >> 4) << 2) + r;
                int col = h * HDIM + nf * 16 + (lane & 15);
                float v = oacc[m][nf][r] / l_run[m][r];
                ao[(size_t)(b * SEQ + qr) * DMODEL + col] = (_Float16)v;
            }
}

// ---------------------------------------------------------------------------
extern "C" void kernel_launch(void* const* d_in, const int* in_sizes, int n_in,
                              void* d_out, int out_size, void* d_ws, size_t ws_size,
                              hipStream_t stream) {
    const float* x  = (const float*)d_in[0];
    const float* Wq = (const float*)d_in[1];
    const float* bq = (const float*)d_in[2];
    const float* Wk = (const float*)d_in[3];
    const float* bk = (const float*)d_in[4];
    const float* Wv = (const float*)d_in[5];
    const float* bv = (const float*)d_in[6];
    const float* Wo = (const float*)d_in[7];
    const float* bo = (const float*)d_in[8];
    float* out = (float*)d_out;

    char* ws = (char*)d_ws;
    _Float16* xs     = (_Float16*)(ws);                    // 16.78 MB [4096][2048]
    _Float16* wqkv16 = (_Float16*)(ws + 16777216);         // 10.49 MB [2560][2048]
    _Float16* wot16  = (_Float16*)(ws + 27262976);         //  8.39 MB [2048][2048]
    _Float16* qkv16  = (_Float16*)(ws + 35651584);         // 20.97 MB [4096][2560]
    _Float16* khb    = (_Float16*)(ws + 56623104);         //  2.10 MB [B][G][S][D]
    _Float16* vtb    = (_Float16*)(ws + 58720256);         //  2.10 MB [B][G][D][S]
    float*    sint   = (float*)(ws + 60817408);            //  0.26 MB
    float*    cost   = (float*)(ws + 61079552);            //  0.26 MB
    float*    bias_c = (float*)(ws + 61341696);            //  10 KB
    _Float16* ao = xs;   // attention output reuses xs (x dead after QKV GEMM)

    rope_table_kernel<<<SEQ * 64 / 256, 256, 0, stream>>>(sint, cost);
    convert_x_kernel<<<ROWS * DMODEL / 8 / 256, 256, 0, stream>>>(x, xs);
    transpose_w_kernel<<<dim3(32, 32), 256, 0, stream>>>(Wq, DMODEL, wqkv16, 0, DMODEL);
    transpose_w_kernel<<<dim3(4, 32),  256, 0, stream>>>(Wk, 256,    wqkv16, 2048, DMODEL);
    transpose_w_kernel<<<dim3(4, 32),  256, 0, stream>>>(Wv, 256,    wqkv16, 2304, DMODEL);
    transpose_w_kernel<<<dim3(32, 32), 256, 0, stream>>>(Wo, DMODEL, wot16,  0, DMODEL);
    bias_cat_kernel<<<10, 256, 0, stream>>>(bq, bk, bv, bias_c);

    // QKV projection: [4096][2048] @ [2048][2560] -> fp16 [4096][2560]
    gemm_fp16_kernel<1><<<(ROWS / 128) * (NQKV / 128), 256, 0, stream>>>(
        xs, wqkv16, bias_c, qkv16, ROWS, NQKV, DMODEL);

    rope_k_kernel<<<(ROWS * NGROUPS * 8) / 256, 256, 0, stream>>>(qkv16, sint, cost, khb);
    transpose_v_kernel<<<dim3(SEQ / 64, HDIM / 64, BATCH * NGROUPS), 256, 0, stream>>>(qkv16, vtb);

    attn_kernel<<<dim3(SEQ / 128, NHEADS, BATCH), 256, 0, stream>>>(
        qkv16, khb, vtb, sint, cost, ao);

    // Output projection: [4096][2048] @ [2048][2048] -> fp32 out
    gemm_fp16_kernel<0><<<(ROWS / 128) * (DMODEL / 128), 256, 0, stream>>>(
        ao, wot16, bo, out, ROWS, DMODEL, DMODEL);
}